// Round 7
// baseline (221.811 us; speedup 1.0000x reference)
//
#include <hip/hip_runtime.h>
#include <hip/hip_bf16.h>
#include <math.h>

typedef short s16x8 __attribute__((ext_vector_type(8)));
typedef short s16x4 __attribute__((ext_vector_type(4)));
typedef _Float16 f16x8 __attribute__((ext_vector_type(8)));
typedef float f32x4 __attribute__((ext_vector_type(4)));

#define MFMA(a, b, c) \
  __builtin_amdgcn_mfma_f32_16x16x32_f16(__builtin_bit_cast(f16x8, a), \
                                         __builtin_bit_cast(f16x8, b), c, 0, 0, 0)

// d_ws: f16 weight fragments only
#define OFF_FWB 0
#define OFF_WQB 8192
#define OFF_WKB 73728
#define OFF_WVB 139264
#define OFF_WOB 204800
#define OFF_W1B 270336
#define OFF_W2B 532480
// total 663552 B

// LDS (bytes): four 16KB frag buffers
#define L_Q 0
#define L_K 16384
#define L_V 32768
#define L_O 49152
#define LDS_BYTES 65536

// Fragment slot bijection (prep kernel only): element (idx,k) of frag-linear 1KB tiles.
__device__ __forceinline__ int fragSlotByte(int idx, int k, int KS) {
  return ((((idx >> 4) * KS + (k >> 5)) << 10)
        | (((idx & 15) | (((k >> 2) & 3) << 4)) << 4)
        | (((k & 3) | (((k >> 4) & 1) << 2)) << 1));
}
__device__ __forceinline__ short f2h(float f) {
  _Float16 h = (_Float16)f;
  return __builtin_bit_cast(short, h);
}
__device__ __forceinline__ unsigned pk_u32(float a, float b) {
  return __builtin_bit_cast(unsigned, __builtin_amdgcn_cvt_pkrtz(a, b));
}
// erf via Abramowitz-Stegun 7.1.26 (|err|<=1.5e-7), exp/rcp on trans pipe
__device__ __forceinline__ float geluf(float v) {
  float z = fabsf(v) * 0.70710678118654752f;
  float t = 1.0f / (1.0f + 0.3275911f * z);
  float p = t * (0.254829592f + t * (-0.284496736f + t * (1.421413741f +
            t * (-1.453152027f + t * 1.061405429f))));
  float erfv = 1.0f - p * __expf(-z * z);
  erfv = copysignf(erfv, v);
  return 0.5f * v * (1.0f + erfv);
}
__device__ __forceinline__ s16x8 pack8(const f32x4& a, const f32x4& b) {
  union { unsigned u[4]; s16x8 s; } z;
  z.u[0] = pk_u32(a[0], a[1]);
  z.u[1] = pk_u32(a[2], a[3]);
  z.u[2] = pk_u32(b[0], b[1]);
  z.u[3] = pk_u32(b[2], b[3]);
  return z.s;
}
__device__ __forceinline__ s16x4 pack4(const f32x4& a) {
  union { unsigned u[2]; s16x4 s; } z;
  z.u[0] = pk_u32(a[0], a[1]);
  z.u[1] = pk_u32(a[2], a[3]);
  return z.s;
}
__device__ __forceinline__ s16x8 fragL(const char* lds, int off, int tile, int lane) {
  return *(const s16x8*)(lds + off + (tile << 10) + (lane << 4));
}
__device__ __forceinline__ s16x8 fragG(const char* wb, int tile, int lane) {
  return *(const s16x8*)(wb + (tile << 10) + (lane << 4));
}

// ---------------- weight prep: all fp32 weights -> f16 frag-linear ----------------
extern "C" __global__ void prep_all(const float* __restrict__ fw, const float* __restrict__ wq,
                                    const float* __restrict__ wk, const float* __restrict__ wv,
                                    const float* __restrict__ wo, const float* __restrict__ w1,
                                    const float* __restrict__ w2, char* __restrict__ dst) {
  for (int e = blockIdx.x * blockDim.x + threadIdx.x; e < 331776; e += gridDim.x * blockDim.x) {
    const float* src; int dstoff, K, N, rel; float sc = 1.f;
    if (e < 4096)        { src = fw; dstoff = OFF_FWB; K = 64;  N = 64;  rel = e; }
    else if (e < 36864)  { src = wq; dstoff = OFF_WQB; K = 64;  N = 64;  rel = e - 4096; sc = 0.25f; }
    else if (e < 69632)  { src = wk; dstoff = OFF_WKB; K = 64;  N = 64;  rel = e - 36864; }
    else if (e < 102400) { src = wv; dstoff = OFF_WVB; K = 64;  N = 64;  rel = e - 69632; }
    else if (e < 135168) { src = wo; dstoff = OFF_WOB; K = 64;  N = 64;  rel = e - 102400; }
    else if (e < 266240) { src = w1; dstoff = OFF_W1B; K = 64;  N = 256; rel = e - 135168; }
    else                 { src = w2; dstoff = OFF_W2B; K = 128; N = 64;  rel = e - 266240; }
    const int KS = K >> 5, pl = K * N;
    const int l = rel / pl, r2 = rel - l * pl;
    const int k = r2 / N, n = r2 - k * N;
    *(short*)(dst + dstoff + (size_t)l * pl * 2 + fragSlotByte(n, k, KS)) = f2h(src[rel] * sc);
  }
}

// ---------------- main fused kernel: 1 block = 1 batch, 8 waves ----------------
extern "C" __global__ __launch_bounds__(512, 2)
void feat_fwd(const float* __restrict__ x, const float* __restrict__ cls_token,
              const float* __restrict__ pos_embed, const float* __restrict__ Wmix,
              const float* __restrict__ ln1_g, const float* __restrict__ ln1_b,
              const float* __restrict__ ln2_g, const float* __restrict__ ln2_b,
              const float* __restrict__ b1, const float* __restrict__ b2,
              const float* __restrict__ Wc, const float* __restrict__ bc,
              float* __restrict__ out, const char* __restrict__ wfrag) {
  extern __shared__ char lds[];
  const int tid = threadIdx.x, lane = tid & 63, wv = tid >> 6, b = blockIdx.x;
  const int l15 = lane & 15, g16 = lane >> 4;
  const f32x4 Z4 = {0.f, 0.f, 0.f, 0.f};

  // Register state (per lane):
  //  hr[nt]     = h[i][c] fp32, i = wv*16 + l15, c = nt*16 + g16*4 + r
  //  hp[ks]     = h as f16 frag, k-range [ks*32, ks*32+32)
  //  af32[q4][jt] = fp32 attn-prob carry; doubles as QK^T MFMA C-init.
  //               elem r holds p[i'][j]: i' = (ih*4+q4)*16 + l15, j = jt*16 + g16*4 + r
  f32x4 hr[4];
  s16x8 hp[2];
  f32x4 af32[4][8];
#pragma unroll
  for (int q4 = 0; q4 < 4; ++q4)
#pragma unroll
    for (int jt = 0; jt < 8; ++jt) af32[q4][jt] = Z4;

  // ---- P0: patch embed (W as A, x as B), C-init = pos_embed -> hr regs ----
  {
    const int i0 = wv * 16 + l15;
    s16x8 xB[2];
#pragma unroll
    for (int ks = 0; ks < 2; ++ks) {
      f32x4 lo, hi;
#pragma unroll
      for (int e = 0; e < 8; ++e) {
        int sidx = i0 * 16 + (e >> 2) * 16 + g16 * 4 + (e & 3);
        if (sidx > 2047) sidx = 2047;  // i0==127 lanes overridden below
        float xv = x[((size_t)b * 2048 + sidx) * 2 + ks];
        if (e < 4) lo[e] = xv; else hi[e - 4] = xv;
      }
      xB[ks] = pack8(lo, hi);
    }
    const char* fwb = wfrag + OFF_FWB;
#pragma unroll
    for (int nt = 0; nt < 4; ++nt) {
      f32x4 a = *(const f32x4*)&pos_embed[i0 * 64 + nt * 16 + g16 * 4];
      a = MFMA(fragG(fwb, nt * 2 + 0, lane), xB[0], a);
      a = MFMA(fragG(fwb, nt * 2 + 1, lane), xB[1], a);
      hr[nt] = a;
    }
    if (i0 == 127) {
#pragma unroll
      for (int nt = 0; nt < 4; ++nt) {
        const f32x4 c4 = *(const f32x4*)&cls_token[nt * 16 + g16 * 4];
        const f32x4 p4 = *(const f32x4*)&pos_embed[127 * 64 + nt * 16 + g16 * 4];
        hr[nt] = c4 + p4;
      }
    }
    hp[0] = pack8(hr[0], hr[1]);
    hp[1] = pack8(hr[2], hr[3]);
  }

  for (int l = 0; l < 8; ++l) {
    // ---- P1: q,k (swapped: W as A) and v (normal) from hp regs -> LDS frags ----
    {
      const char* wq = wfrag + OFF_WQB + l * 8192;
      const char* wk = wfrag + OFF_WKB + l * 8192;
      const char* wvp = wfrag + OFF_WVB + l * 8192;
      f32x4 aq[4], ak[4], av[4];
#pragma unroll
      for (int nt = 0; nt < 4; ++nt) { aq[nt] = Z4; ak[nt] = Z4; av[nt] = Z4; }
#pragma unroll
      for (int ks = 0; ks < 2; ++ks)
#pragma unroll
        for (int nt = 0; nt < 4; ++nt) {
          aq[nt] = MFMA(fragG(wq, nt * 2 + ks, lane), hp[ks], aq[nt]);
          ak[nt] = MFMA(fragG(wk, nt * 2 + ks, lane), hp[ks], ak[nt]);
          av[nt] = MFMA(hp[ks], fragG(wvp, nt * 2 + ks, lane), av[nt]);
        }
#pragma unroll
      for (int ksp = 0; ksp < 2; ++ksp) {
        *(s16x8*)(lds + L_Q + (((wv * 2 + ksp) << 10) | (lane << 4))) = pack8(aq[2 * ksp], aq[2 * ksp + 1]);
        *(s16x8*)(lds + L_K + (((wv * 2 + ksp) << 10) | (lane << 4))) = pack8(ak[2 * ksp], ak[2 * ksp + 1]);
      }
#pragma unroll
      for (int nt = 0; nt < 4; ++nt)  // v transposed frag: idx=vcol, k=row
        *(s16x4*)(lds + L_V + (((nt * 4 + (wv >> 1)) << 10) | (lane << 4) | ((wv & 1) << 3))) = pack4(av[nt]);
    }
    __syncthreads();

    // ---- P2: S^T per head g (A=k, B=q*wmix), C-init = fp32 carry -> softmax (no max-shift) ----
    {
      const int g = wv >> 1, ih = wv & 1;
      s16x8 wmv[2];
      {
        const float w0 = Wmix[(l * 4 + 0) * 4 + g], w1_ = Wmix[(l * 4 + 1) * 4 + g];
        const float w2_ = Wmix[(l * 4 + 2) * 4 + g], w3_ = Wmix[(l * 4 + 3) * 4 + g];
        union { unsigned u[4]; s16x8 s; } u0, u1;
        u0.u[0] = u0.u[1] = pk_u32(w0, w0);
        u0.u[2] = u0.u[3] = pk_u32(w1_, w1_);
        u1.u[0] = u1.u[1] = pk_u32(w2_, w2_);
        u1.u[2] = u1.u[3] = pk_u32(w3_, w3_);
        wmv[0] = u0.s; wmv[1] = u1.s;
      }
#pragma unroll
      for (int q4 = 0; q4 < 4; ++q4) {
        const int ti = ih * 4 + q4;
#pragma unroll
        for (int ks = 0; ks < 2; ++ks) {
          const s16x8 qr = fragL(lds, L_Q, ti * 2 + ks, lane);
          const f16x8 qm = __builtin_bit_cast(f16x8, qr) * __builtin_bit_cast(f16x8, wmv[ks]);
#pragma unroll
          for (int jt = 0; jt < 8; ++jt)
            af32[q4][jt] = MFMA(fragL(lds, L_K, jt * 2 + ks, lane), qm, af32[q4][jt]);
        }
        // softmax over j (logits bounded |l|<~5: exp never overflows; shift-invariant)
        float s0 = 0.f, s1 = 0.f, s2 = 0.f, s3 = 0.f;
#pragma unroll
        for (int jt = 0; jt < 8; ++jt) {
          const float e0 = __expf(af32[q4][jt][0]);
          const float e1 = __expf(af32[q4][jt][1]);
          const float e2 = __expf(af32[q4][jt][2]);
          const float e3 = __expf(af32[q4][jt][3]);
          af32[q4][jt][0] = e0; af32[q4][jt][1] = e1;
          af32[q4][jt][2] = e2; af32[q4][jt][3] = e3;
          s0 += e0; s1 += e1; s2 += e2; s3 += e3;
        }
        float s = (s0 + s1) + (s2 + s3);
        s += __shfl_xor(s, 16); s += __shfl_xor(s, 32);
        const float inv = 1.f / s;
#pragma unroll
        for (int jt = 0; jt < 8; ++jt) {
          af32[q4][jt][0] *= inv; af32[q4][jt][1] *= inv;
          af32[q4][jt][2] *= inv; af32[q4][jt][3] *= inv;
        }
      }
    }
    // no barrier: P3 reads L_V (ready) + own af32; writes L_O (disjoint from L_Q/L_K)

    // ---- P3: o_g = v_g^T-frags (A) x p (B, packed on the fly) -> L_O frags ----
    {
      const int g = wv >> 1, ih = wv & 1;
#pragma unroll
      for (int q4 = 0; q4 < 4; ++q4) {
        const int ti = ih * 4 + q4;
        f32x4 a = Z4;
#pragma unroll
        for (int ks = 0; ks < 4; ++ks) {
          const s16x8 pfrag = pack8(af32[q4][2 * ks], af32[q4][2 * ks + 1]);
          a = MFMA(fragL(lds, L_V, g * 4 + ks, lane), pfrag, a);
        }
        *(s16x4*)(lds + L_O + (((ti * 2 + (g >> 1)) << 10) | (lane << 4) | ((g & 1) << 3))) = pack4(a);
      }
    }
    __syncthreads();

    // ---- P4: r = o@Wo (Wo as A, C-init = hr); h = LN1(h + r) -> hr, hp ----
    {
      const char* wo = wfrag + OFF_WOB + l * 8192;
      s16x8 ofr[2];
      ofr[0] = fragL(lds, L_O, wv * 2 + 0, lane);
      ofr[1] = fragL(lds, L_O, wv * 2 + 1, lane);
      f32x4 vv[4];
      float s = 0.f;
#pragma unroll
      for (int nt = 0; nt < 4; ++nt) {
        f32x4 a = hr[nt];
        a = MFMA(fragG(wo, nt * 2 + 0, lane), ofr[0], a);
        a = MFMA(fragG(wo, nt * 2 + 1, lane), ofr[1], a);
        vv[nt] = a;
        s += (a[0] + a[1]) + (a[2] + a[3]);
      }
      s += __shfl_xor(s, 16); s += __shfl_xor(s, 32);
      const float mu = s * 0.015625f;
      float sq = 0.f;
#pragma unroll
      for (int nt = 0; nt < 4; ++nt)
#pragma unroll
        for (int r = 0; r < 4; ++r) { float d = vv[nt][r] - mu; sq += d * d; }
      sq += __shfl_xor(sq, 16); sq += __shfl_xor(sq, 32);
      const float rs = rsqrtf(sq * 0.015625f + 1e-5f);
#pragma unroll
      for (int nt = 0; nt < 4; ++nt) {
        const f32x4 g4 = *(const f32x4*)&ln1_g[l * 64 + nt * 16 + g16 * 4];
        const f32x4 b4 = *(const f32x4*)&ln1_b[l * 64 + nt * 16 + g16 * 4];
#pragma unroll
        for (int r = 0; r < 4; ++r)
          hr[nt][r] = (vv[nt][r] - mu) * rs * g4[r] + b4[r];
      }
      hp[0] = pack8(hr[0], hr[1]);
      hp[1] = pack8(hr[2], hr[3]);
    }

    // ---- P5+P6 fused: u=h@W1 (C-init = b1) -> GLU -> f -> h = LN2(h + f@W2 + b2) ----
    {
      const char* w1 = wfrag + OFF_W1B + l * 32768;
      const char* w2 = wfrag + OFF_W2B + l * 16384;
      f32x4 acc6[4];
#pragma unroll
      for (int nt = 0; nt < 4; ++nt) acc6[nt] = hr[nt];  // C-init: residual
#pragma unroll
      for (int ks6 = 0; ks6 < 4; ++ks6) {
        union { unsigned u[4]; s16x8 s; } fb;
#pragma unroll
        for (int half = 0; half < 2; ++half) {
          const int mtp = ks6 * 2 + half;
          f32x4 a1 = *(const f32x4*)&b1[l * 256 + mtp * 16 + g16 * 4];
          f32x4 a2 = *(const f32x4*)&b1[l * 256 + 128 + mtp * 16 + g16 * 4];
#pragma unroll
          for (int ks = 0; ks < 2; ++ks) {
            a1 = MFMA(fragG(w1, mtp * 2 + ks, lane), hp[ks], a1);
            a2 = MFMA(fragG(w1, (mtp + 8) * 2 + ks, lane), hp[ks], a2);
          }
          float fv[4];
#pragma unroll
          for (int r = 0; r < 4; ++r)
            fv[r] = a1[r] * geluf(a2[r]) + a2[r] * geluf(a1[r]);
          fb.u[half * 2 + 0] = pk_u32(fv[0], fv[1]);
          fb.u[half * 2 + 1] = pk_u32(fv[2], fv[3]);
        }
#pragma unroll
        for (int nt = 0; nt < 4; ++nt)
          acc6[nt] = MFMA(fragG(w2, nt * 4 + ks6, lane), fb.s, acc6[nt]);
      }
      // + b2, LN2
      f32x4 vv[4];
      float s = 0.f;
#pragma unroll
      for (int nt = 0; nt < 4; ++nt) {
        const f32x4 bb = *(const f32x4*)&b2[l * 64 + nt * 16 + g16 * 4];
        vv[nt] = acc6[nt] + bb;
        s += (vv[nt][0] + vv[nt][1]) + (vv[nt][2] + vv[nt][3]);
      }
      s += __shfl_xor(s, 16); s += __shfl_xor(s, 32);
      const float mu = s * 0.015625f;
      float sq = 0.f;
#pragma unroll
      for (int nt = 0; nt < 4; ++nt)
#pragma unroll
        for (int r = 0; r < 4; ++r) { float d = vv[nt][r] - mu; sq += d * d; }
      sq += __shfl_xor(sq, 16); sq += __shfl_xor(sq, 32);
      const float rs = rsqrtf(sq * 0.015625f + 1e-5f);
#pragma unroll
      for (int nt = 0; nt < 4; ++nt) {
        const f32x4 g4 = *(const f32x4*)&ln2_g[l * 64 + nt * 16 + g16 * 4];
        const f32x4 b4 = *(const f32x4*)&ln2_b[l * 64 + nt * 16 + g16 * 4];
#pragma unroll
        for (int r = 0; r < 4; ++r)
          hr[nt][r] = (vv[nt][r] - mu) * rs * g4[r] + b4[r];
      }
      hp[0] = pack8(hr[0], hr[1]);
      hp[1] = pack8(hr[2], hr[3]);
    }
  }

  // ---- classifier head on row 127 ----
  float* scr = (float*)(lds + L_Q);
  if (wv == 7 && l15 == 15) {
#pragma unroll
    for (int nt = 0; nt < 4; ++nt)
#pragma unroll
      for (int r = 0; r < 4; ++r) scr[nt * 16 + g16 * 4 + r] = hr[nt][r];
  }
  __syncthreads();
  if (wv == 0) {
    const float hc = scr[lane];
    float lg[11];
#pragma unroll
    for (int kc = 0; kc < 11; ++kc) {
      float p = hc * Wc[lane * 11 + kc];
      p += __shfl_xor(p, 1);  p += __shfl_xor(p, 2);  p += __shfl_xor(p, 4);
      p += __shfl_xor(p, 8);  p += __shfl_xor(p, 16); p += __shfl_xor(p, 32);
      lg[kc] = p + bc[kc];
    }
    float mx = lg[0];
#pragma unroll
    for (int kc = 1; kc < 11; ++kc) mx = fmaxf(mx, lg[kc]);
    float s = 0.f;
#pragma unroll
    for (int kc = 0; kc < 11; ++kc) s += __expf(lg[kc] - mx);
    const float inv = 1.f / s;
    if (lane < 11) out[b * 11 + lane] = __expf(lg[lane] - mx) * inv;
  }
}

extern "C" void kernel_launch(void* const* d_in, const int* in_sizes, int n_in,
                              void* d_out, int out_size, void* d_ws, size_t ws_size,
                              hipStream_t stream) {
  const float* x         = (const float*)d_in[0];
  const float* frame_W   = (const float*)d_in[1];
  const float* cls_token = (const float*)d_in[2];
  const float* pos_embed = (const float*)d_in[3];
  const float* Wq        = (const float*)d_in[4];
  const float* Wk        = (const float*)d_in[5];
  const float* Wv        = (const float*)d_in[6];
  const float* Wmix      = (const float*)d_in[7];
  const float* Wo        = (const float*)d_in[8];
  const float* ln1_g     = (const float*)d_in[9];
  const float* ln1_b     = (const float*)d_in[10];
  const float* ln2_g     = (const float*)d_in[11];
  const float* ln2_b     = (const float*)d_in[12];
  const float* W1        = (const float*)d_in[13];
  const float* b1        = (const float*)d_in[14];
  const float* W2        = (const float*)d_in[15];
  const float* b2        = (const float*)d_in[16];
  const float* Wc        = (const float*)d_in[17];
  const float* bc        = (const float*)d_in[18];
  float* out = (float*)d_out;
  char* wfrag = (char*)d_ws;  // 663,552 B of f16 weight fragments

  prep_all<<<162, 256, 0, stream>>>(frame_W, Wq, Wk, Wv, Wo, W1, W2, wfrag);

  (void)hipFuncSetAttribute((const void*)feat_fwd, hipFuncAttributeMaxDynamicSharedMemorySize, LDS_BYTES);
  feat_fwd<<<dim3(256), dim3(512), LDS_BYTES, stream>>>(
      x, cls_token, pos_embed, Wmix, ln1_g, ln1_b, ln2_g, ln2_b,
      b1, b2, Wc, bc, out, wfrag);
}

// Round 8
// 135.434 us; speedup vs baseline: 1.6378x; 1.6378x over previous
//
#include <hip/hip_runtime.h>
#include <hip/hip_bf16.h>
#include <math.h>

typedef short s16x8 __attribute__((ext_vector_type(8)));
typedef short s16x4 __attribute__((ext_vector_type(4)));
typedef _Float16 f16x8 __attribute__((ext_vector_type(8)));
typedef float f32x4 __attribute__((ext_vector_type(4)));

#define MFMA(a, b, c) \
  __builtin_amdgcn_mfma_f32_16x16x32_f16(__builtin_bit_cast(f16x8, a), \
                                         __builtin_bit_cast(f16x8, b), c, 0, 0, 0)

#if __has_builtin(__builtin_amdgcn_exp2f)
#define EXP2(x) __builtin_amdgcn_exp2f(x)
#else
#define EXP2(x) exp2f(x)
#endif
#if __has_builtin(__builtin_amdgcn_rcpf)
#define RCP(x) __builtin_amdgcn_rcpf(x)
#else
#define RCP(x) (1.0f / (x))
#endif

#define LOG2E 1.44269504088896340736f
#define LN2   0.69314718055994530942f

// d_ws: f16 weight fragments only
#define OFF_FWB 0
#define OFF_WQB 8192
#define OFF_WKB 73728
#define OFF_WVB 139264
#define OFF_WOB 204800
#define OFF_W1B 270336
#define OFF_W2B 532480
// total 663552 B

// LDS (bytes): four 16KB frag buffers
#define L_Q 0
#define L_K 16384
#define L_V 32768
#define L_O 49152
#define LDS_BYTES 65536

// Fragment slot bijection (prep kernel only): element (idx,k) of frag-linear 1KB tiles.
__device__ __forceinline__ int fragSlotByte(int idx, int k, int KS) {
  return ((((idx >> 4) * KS + (k >> 5)) << 10)
        | (((idx & 15) | (((k >> 2) & 3) << 4)) << 4)
        | (((k & 3) | (((k >> 4) & 1) << 2)) << 1));
}
__device__ __forceinline__ short f2h(float f) {
  _Float16 h = (_Float16)f;
  return __builtin_bit_cast(short, h);
}
__device__ __forceinline__ float h2f(short s) {
  return (float)__builtin_bit_cast(_Float16, s);
}
__device__ __forceinline__ unsigned pk_u32(float a, float b) {
  return __builtin_bit_cast(unsigned, __builtin_amdgcn_cvt_pkrtz(a, b));
}
// erf via Abramowitz-Stegun 7.1.25 3-term (|err|<=2.5e-5)
__device__ __forceinline__ float geluf(float v) {
  float z = fabsf(v) * 0.70710678118654752f;
  float t = RCP(1.0f + 0.47047f * z);
  float p = t * (0.3480242f + t * (-0.0958798f + t * 0.7478556f));
  float erfv = 1.0f - p * __expf(-z * z);
  erfv = copysignf(erfv, v);
  return 0.5f * v * (1.0f + erfv);
}
__device__ __forceinline__ s16x8 pack8(const f32x4& a, const f32x4& b) {
  union { unsigned u[4]; s16x8 s; } z;
  z.u[0] = pk_u32(a[0], a[1]);
  z.u[1] = pk_u32(a[2], a[3]);
  z.u[2] = pk_u32(b[0], b[1]);
  z.u[3] = pk_u32(b[2], b[3]);
  return z.s;
}
__device__ __forceinline__ s16x4 pack4(const f32x4& a) {
  union { unsigned u[2]; s16x4 s; } z;
  z.u[0] = pk_u32(a[0], a[1]);
  z.u[1] = pk_u32(a[2], a[3]);
  return z.s;
}
__device__ __forceinline__ s16x8 fragL(const char* lds, int off, int tile, int lane) {
  return *(const s16x8*)(lds + off + (tile << 10) + (lane << 4));
}
__device__ __forceinline__ s16x8 fragG(const char* wb, int tile, int lane) {
  return *(const s16x8*)(wb + (tile << 10) + (lane << 4));
}

// ---------------- weight prep: all fp32 weights -> f16 frag-linear ----------------
// Wq pre-scaled by 1/4 (1/sqrt(DQK)); Wo pre-scaled by ln2 to compensate the
// p*log2e carry domain (exact linear compensation).
extern "C" __global__ void prep_all(const float* __restrict__ fw, const float* __restrict__ wq,
                                    const float* __restrict__ wk, const float* __restrict__ wv,
                                    const float* __restrict__ wo, const float* __restrict__ w1,
                                    const float* __restrict__ w2, char* __restrict__ dst) {
  for (int e = blockIdx.x * blockDim.x + threadIdx.x; e < 331776; e += gridDim.x * blockDim.x) {
    const float* src; int dstoff, K, N, rel; float sc = 1.f;
    if (e < 4096)        { src = fw; dstoff = OFF_FWB; K = 64;  N = 64;  rel = e; }
    else if (e < 36864)  { src = wq; dstoff = OFF_WQB; K = 64;  N = 64;  rel = e - 4096; sc = 0.25f; }
    else if (e < 69632)  { src = wk; dstoff = OFF_WKB; K = 64;  N = 64;  rel = e - 36864; }
    else if (e < 102400) { src = wv; dstoff = OFF_WVB; K = 64;  N = 64;  rel = e - 69632; }
    else if (e < 135168) { src = wo; dstoff = OFF_WOB; K = 64;  N = 64;  rel = e - 102400; sc = LN2; }
    else if (e < 266240) { src = w1; dstoff = OFF_W1B; K = 64;  N = 256; rel = e - 135168; }
    else                 { src = w2; dstoff = OFF_W2B; K = 128; N = 64;  rel = e - 266240; }
    const int KS = K >> 5, pl = K * N;
    const int l = rel / pl, r2 = rel - l * pl;
    const int k = r2 / N, n = r2 - k * N;
    *(short*)(dst + dstoff + (size_t)l * pl * 2 + fragSlotByte(n, k, KS)) = f2h(src[rel] * sc);
  }
}

// ---------------- main fused kernel: 1 block = 1 batch, 8 waves ----------------
extern "C" __global__ __launch_bounds__(512)
void feat_fwd(const float* __restrict__ x, const float* __restrict__ cls_token,
              const float* __restrict__ pos_embed, const float* __restrict__ Wmix,
              const float* __restrict__ ln1_g, const float* __restrict__ ln1_b,
              const float* __restrict__ ln2_g, const float* __restrict__ ln2_b,
              const float* __restrict__ b1, const float* __restrict__ b2,
              const float* __restrict__ Wc, const float* __restrict__ bc,
              float* __restrict__ out, const char* __restrict__ wfrag) {
  extern __shared__ char lds[];
  const int tid = threadIdx.x, lane = tid & 63, wv = tid >> 6, b = blockIdx.x;
  const int l15 = lane & 15, g16 = lane >> 4;
  const f32x4 Z4 = {0.f, 0.f, 0.f, 0.f};

  // Register state (per lane):
  //  hr[nt]    = h[i][c] fp32, i = wv*16 + l15, c = nt*16 + g16*4 + r
  //  hp[ks]    = h as f16 frag, k-range [ks*32, ks*32+32)
  //  af[q4][ks]= attn carry stored as p*LOG2E in f16 frag layout
  //              (PV scale compensated by Wo' = Wo*LN2)
  f32x4 hr[4];
  s16x8 hp[2];
  s16x8 af[4][4] = {};

  // ---- P0: patch embed (W as A, x as B), C-init = pos_embed -> hr regs ----
  {
    const int i0 = wv * 16 + l15;
    s16x8 xB[2];
#pragma unroll
    for (int ks = 0; ks < 2; ++ks) {
      f32x4 lo, hi;
#pragma unroll
      for (int e = 0; e < 8; ++e) {
        int sidx = i0 * 16 + (e >> 2) * 16 + g16 * 4 + (e & 3);
        if (sidx > 2047) sidx = 2047;  // i0==127 lanes overridden below
        float xv = x[((size_t)b * 2048 + sidx) * 2 + ks];
        if (e < 4) lo[e] = xv; else hi[e - 4] = xv;
      }
      xB[ks] = pack8(lo, hi);
    }
    const char* fwb = wfrag + OFF_FWB;
#pragma unroll
    for (int nt = 0; nt < 4; ++nt) {
      f32x4 a = *(const f32x4*)&pos_embed[i0 * 64 + nt * 16 + g16 * 4];
      a = MFMA(fragG(fwb, nt * 2 + 0, lane), xB[0], a);
      a = MFMA(fragG(fwb, nt * 2 + 1, lane), xB[1], a);
      hr[nt] = a;
    }
    if (i0 == 127) {
#pragma unroll
      for (int nt = 0; nt < 4; ++nt) {
        const f32x4 c4 = *(const f32x4*)&cls_token[nt * 16 + g16 * 4];
        const f32x4 p4 = *(const f32x4*)&pos_embed[127 * 64 + nt * 16 + g16 * 4];
        hr[nt] = c4 + p4;
      }
    }
    hp[0] = pack8(hr[0], hr[1]);
    hp[1] = pack8(hr[2], hr[3]);
  }

  for (int l = 0; l < 8; ++l) {
    // ---- P1: q,k (swapped: W as A) and v (normal) from hp regs -> LDS frags ----
    {
      const char* wq = wfrag + OFF_WQB + l * 8192;
      const char* wk = wfrag + OFF_WKB + l * 8192;
      const char* wvp = wfrag + OFF_WVB + l * 8192;
      f32x4 aq[4], ak[4], av[4];
#pragma unroll
      for (int nt = 0; nt < 4; ++nt) { aq[nt] = Z4; ak[nt] = Z4; av[nt] = Z4; }
#pragma unroll
      for (int ks = 0; ks < 2; ++ks)
#pragma unroll
        for (int nt = 0; nt < 4; ++nt) {
          aq[nt] = MFMA(fragG(wq, nt * 2 + ks, lane), hp[ks], aq[nt]);
          ak[nt] = MFMA(fragG(wk, nt * 2 + ks, lane), hp[ks], ak[nt]);
          av[nt] = MFMA(hp[ks], fragG(wvp, nt * 2 + ks, lane), av[nt]);
        }
#pragma unroll
      for (int ksp = 0; ksp < 2; ++ksp) {
        *(s16x8*)(lds + L_Q + (((wv * 2 + ksp) << 10) | (lane << 4))) = pack8(aq[2 * ksp], aq[2 * ksp + 1]);
        *(s16x8*)(lds + L_K + (((wv * 2 + ksp) << 10) | (lane << 4))) = pack8(ak[2 * ksp], ak[2 * ksp + 1]);
      }
#pragma unroll
      for (int nt = 0; nt < 4; ++nt)  // v transposed frag: idx=vcol, k=row
        *(s16x4*)(lds + L_V + (((nt * 4 + (wv >> 1)) << 10) | (lane << 4) | ((wv & 1) << 3))) = pack4(av[nt]);
    }
    __syncthreads();

    // ---- P2: acc = LOG2E*(S + carry) via C-init; p*LOG2E = exp2(acc)/sum ----
    {
      const int g = wv >> 1, ih = wv & 1;
      s16x8 wmv[2];
      {
        // wmix * LOG2E folded into the q rescale
        const float w0 = Wmix[(l * 4 + 0) * 4 + g] * LOG2E, w1_ = Wmix[(l * 4 + 1) * 4 + g] * LOG2E;
        const float w2_ = Wmix[(l * 4 + 2) * 4 + g] * LOG2E, w3_ = Wmix[(l * 4 + 3) * 4 + g] * LOG2E;
        union { unsigned u[4]; s16x8 s; } u0, u1;
        u0.u[0] = u0.u[1] = pk_u32(w0, w0);
        u0.u[2] = u0.u[3] = pk_u32(w1_, w1_);
        u1.u[0] = u1.u[1] = pk_u32(w2_, w2_);
        u1.u[2] = u1.u[3] = pk_u32(w3_, w3_);
        wmv[0] = u0.s; wmv[1] = u1.s;
      }
#pragma unroll
      for (int q4 = 0; q4 < 4; ++q4) {
        const int ti = ih * 4 + q4;
        f32x4 acc[8];
        if (l > 0) {
          // C-init = carry (already p*LOG2E): saves the post-add
#pragma unroll
          for (int jt = 0; jt < 8; ++jt)
#pragma unroll
            for (int r = 0; r < 4; ++r)
              acc[jt][r] = h2f(af[q4][jt >> 1][((jt & 1) << 2) | r]);
        } else {
#pragma unroll
          for (int jt = 0; jt < 8; ++jt) acc[jt] = Z4;
        }
#pragma unroll
        for (int ks = 0; ks < 2; ++ks) {
          const s16x8 qr = fragL(lds, L_Q, ti * 2 + ks, lane);
          const f16x8 qm = __builtin_bit_cast(f16x8, qr) * __builtin_bit_cast(f16x8, wmv[ks]);
#pragma unroll
          for (int jt = 0; jt < 8; ++jt)
            acc[jt] = MFMA(fragL(lds, L_K, jt * 2 + ks, lane), qm, acc[jt]);
        }
        // softmax, no max-shift (|logit|<~5): e = exp2(acc) directly
        float s0 = 0.f, s1 = 0.f, s2 = 0.f, s3 = 0.f;
#pragma unroll
        for (int jt = 0; jt < 8; ++jt) {
          const float e0 = EXP2(acc[jt][0]);
          const float e1 = EXP2(acc[jt][1]);
          const float e2 = EXP2(acc[jt][2]);
          const float e3 = EXP2(acc[jt][3]);
          acc[jt][0] = e0; acc[jt][1] = e1;
          acc[jt][2] = e2; acc[jt][3] = e3;
          s0 += e0; s1 += e1; s2 += e2; s3 += e3;
        }
        float s = (s0 + s1) + (s2 + s3);
        s += __shfl_xor(s, 16); s += __shfl_xor(s, 32);
        const float invl = RCP(s) * LOG2E;  // normalize AND move to p*LOG2E domain
#pragma unroll
        for (int jt = 0; jt < 8; ++jt) {
          acc[jt][0] *= invl; acc[jt][1] *= invl;
          acc[jt][2] *= invl; acc[jt][3] *= invl;
        }
#pragma unroll
        for (int ks3 = 0; ks3 < 4; ++ks3)
          af[q4][ks3] = pack8(acc[2 * ks3], acc[2 * ks3 + 1]);
      }
    }
    // no barrier: P3 reads L_V (ready) + own af; writes L_O (disjoint from L_Q/L_K)

    // ---- P3: o' = v^T-frags (A) x (p*LOG2E) (B=af) -> L_O frags ----
    {
      const int g = wv >> 1, ih = wv & 1;
#pragma unroll
      for (int q4 = 0; q4 < 4; ++q4) {
        const int ti = ih * 4 + q4;
        f32x4 a = Z4;
#pragma unroll
        for (int ks = 0; ks < 4; ++ks)
          a = MFMA(fragL(lds, L_V, g * 4 + ks, lane), af[q4][ks], a);
        *(s16x4*)(lds + L_O + (((ti * 2 + (g >> 1)) << 10) | (lane << 4) | ((g & 1) << 3))) = pack4(a);
      }
    }
    __syncthreads();

    // ---- P4: r = o'@Wo' (Wo' = Wo*LN2, C-init = hr); h = LN1 -> hr, hp ----
    {
      const char* wo = wfrag + OFF_WOB + l * 8192;
      s16x8 ofr[2];
      ofr[0] = fragL(lds, L_O, wv * 2 + 0, lane);
      ofr[1] = fragL(lds, L_O, wv * 2 + 1, lane);
      f32x4 vv[4];
      float s = 0.f;
#pragma unroll
      for (int nt = 0; nt < 4; ++nt) {
        f32x4 a = hr[nt];
        a = MFMA(fragG(wo, nt * 2 + 0, lane), ofr[0], a);
        a = MFMA(fragG(wo, nt * 2 + 1, lane), ofr[1], a);
        vv[nt] = a;
        s += (a[0] + a[1]) + (a[2] + a[3]);
      }
      s += __shfl_xor(s, 16); s += __shfl_xor(s, 32);
      const float mu = s * 0.015625f;
      float sq = 0.f;
#pragma unroll
      for (int nt = 0; nt < 4; ++nt)
#pragma unroll
        for (int r = 0; r < 4; ++r) { float d = vv[nt][r] - mu; sq += d * d; }
      sq += __shfl_xor(sq, 16); sq += __shfl_xor(sq, 32);
      const float rs = rsqrtf(sq * 0.015625f + 1e-5f);
#pragma unroll
      for (int nt = 0; nt < 4; ++nt) {
        const f32x4 g4 = *(const f32x4*)&ln1_g[l * 64 + nt * 16 + g16 * 4];
        const f32x4 b4 = *(const f32x4*)&ln1_b[l * 64 + nt * 16 + g16 * 4];
#pragma unroll
        for (int r = 0; r < 4; ++r)
          hr[nt][r] = (vv[nt][r] - mu) * rs * g4[r] + b4[r];
      }
      hp[0] = pack8(hr[0], hr[1]);
      hp[1] = pack8(hr[2], hr[3]);
    }

    // ---- P5+P6 fused: u=h@W1 (C-init b1) -> GLU -> f -> h = LN2(h + f@W2 + b2) ----
    {
      const char* w1 = wfrag + OFF_W1B + l * 32768;
      const char* w2 = wfrag + OFF_W2B + l * 16384;
      f32x4 acc6[4];
#pragma unroll
      for (int nt = 0; nt < 4; ++nt) {
        const f32x4 bb = *(const f32x4*)&b2[l * 64 + nt * 16 + g16 * 4];
        acc6[nt] = hr[nt] + bb;  // C-init: residual + b2
      }
#pragma unroll
      for (int ks6 = 0; ks6 < 4; ++ks6) {
        union { unsigned u[4]; s16x8 s; } fb;
#pragma unroll
        for (int half = 0; half < 2; ++half) {
          const int mtp = ks6 * 2 + half;
          f32x4 a1 = *(const f32x4*)&b1[l * 256 + mtp * 16 + g16 * 4];
          f32x4 a2 = *(const f32x4*)&b1[l * 256 + 128 + mtp * 16 + g16 * 4];
#pragma unroll
          for (int ks = 0; ks < 2; ++ks) {
            a1 = MFMA(fragG(w1, mtp * 2 + ks, lane), hp[ks], a1);
            a2 = MFMA(fragG(w1, (mtp + 8) * 2 + ks, lane), hp[ks], a2);
          }
          float fv[4];
#pragma unroll
          for (int r = 0; r < 4; ++r)
            fv[r] = a1[r] * geluf(a2[r]) + a2[r] * geluf(a1[r]);
          fb.u[half * 2 + 0] = pk_u32(fv[0], fv[1]);
          fb.u[half * 2 + 1] = pk_u32(fv[2], fv[3]);
        }
#pragma unroll
        for (int nt = 0; nt < 4; ++nt)
          acc6[nt] = MFMA(fragG(w2, nt * 4 + ks6, lane), fb.s, acc6[nt]);
      }
      // LN2
      float s = 0.f;
#pragma unroll
      for (int nt = 0; nt < 4; ++nt)
        s += (acc6[nt][0] + acc6[nt][1]) + (acc6[nt][2] + acc6[nt][3]);
      s += __shfl_xor(s, 16); s += __shfl_xor(s, 32);
      const float mu = s * 0.015625f;
      float sq = 0.f;
#pragma unroll
      for (int nt = 0; nt < 4; ++nt)
#pragma unroll
        for (int r = 0; r < 4; ++r) { float d = acc6[nt][r] - mu; sq += d * d; }
      sq += __shfl_xor(sq, 16); sq += __shfl_xor(sq, 32);
      const float rs = rsqrtf(sq * 0.015625f + 1e-5f);
#pragma unroll
      for (int nt = 0; nt < 4; ++nt) {
        const f32x4 g4 = *(const f32x4*)&ln2_g[l * 64 + nt * 16 + g16 * 4];
        const f32x4 b4 = *(const f32x4*)&ln2_b[l * 64 + nt * 16 + g16 * 4];
#pragma unroll
        for (int r = 0; r < 4; ++r)
          hr[nt][r] = (acc6[nt][r] - mu) * rs * g4[r] + b4[r];
      }
      hp[0] = pack8(hr[0], hr[1]);
      hp[1] = pack8(hr[2], hr[3]);
    }
  }

  // ---- classifier head on row 127 ----
  float* scr = (float*)(lds + L_Q);
  if (wv == 7 && l15 == 15) {
#pragma unroll
    for (int nt = 0; nt < 4; ++nt)
#pragma unroll
      for (int r = 0; r < 4; ++r) scr[nt * 16 + g16 * 4 + r] = hr[nt][r];
  }
  __syncthreads();
  if (wv == 0) {
    const float hc = scr[lane];
    float lg[11];
#pragma unroll
    for (int kc = 0; kc < 11; ++kc) {
      float p = hc * Wc[lane * 11 + kc];
      p += __shfl_xor(p, 1);  p += __shfl_xor(p, 2);  p += __shfl_xor(p, 4);
      p += __shfl_xor(p, 8);  p += __shfl_xor(p, 16); p += __shfl_xor(p, 32);
      lg[kc] = p + bc[kc];
    }
    float mx = lg[0];
#pragma unroll
    for (int kc = 1; kc < 11; ++kc) mx = fmaxf(mx, lg[kc]);
    float s = 0.f;
#pragma unroll
    for (int kc = 0; kc < 11; ++kc) s += __expf(lg[kc] - mx);
    const float inv = 1.f / s;
    if (lane < 11) out[b * 11 + lane] = __expf(lg[lane] - mx) * inv;
  }
}

extern "C" void kernel_launch(void* const* d_in, const int* in_sizes, int n_in,
                              void* d_out, int out_size, void* d_ws, size_t ws_size,
                              hipStream_t stream) {
  const float* x         = (const float*)d_in[0];
  const float* frame_W   = (const float*)d_in[1];
  const float* cls_token = (const float*)d_in[2];
  const float* pos_embed = (const float*)d_in[3];
  const float* Wq        = (const float*)d_in[4];
  const float* Wk        = (const float*)d_in[5];
  const float* Wv        = (const float*)d_in[6];
  const float* Wmix      = (const float*)d_in[7];
  const float* Wo        = (const float*)d_in[8];
  const float* ln1_g     = (const float*)d_in[9];
  const float* ln1_b     = (const float*)d_in[10];
  const float* ln2_g     = (const float*)d_in[11];
  const float* ln2_b     = (const float*)d_in[12];
  const float* W1        = (const float*)d_in[13];
  const float* b1        = (const float*)d_in[14];
  const float* W2        = (const float*)d_in[15];
  const float* b2        = (const float*)d_in[16];
  const float* Wc        = (const float*)d_in[17];
  const float* bc        = (const float*)d_in[18];
  float* out = (float*)d_out;
  char* wfrag = (char*)d_ws;  // 663,552 B of f16 weight fragments

  prep_all<<<162, 256, 0, stream>>>(frame_W, Wq, Wk, Wv, Wo, W1, W2, wfrag);

  (void)hipFuncSetAttribute((const void*)feat_fwd, hipFuncAttributeMaxDynamicSharedMemorySize, LDS_BYTES);
  feat_fwd<<<dim3(256), dim3(512), LDS_BYTES, stream>>>(
      x, cls_token, pos_embed, Wmix, ln1_g, ln1_b, ln2_g, ln2_b,
      b1, b2, Wc, bc, out, wfrag);
}

// Round 9
// 123.711 us; speedup vs baseline: 1.7930x; 1.0948x over previous
//
#include <hip/hip_runtime.h>
#include <hip/hip_bf16.h>
#include <math.h>

typedef short s16x8 __attribute__((ext_vector_type(8)));
typedef short s16x4 __attribute__((ext_vector_type(4)));
typedef _Float16 f16x8 __attribute__((ext_vector_type(8)));
typedef float f32x4 __attribute__((ext_vector_type(4)));

#define MFMA(a, b, c) \
  __builtin_amdgcn_mfma_f32_16x16x32_f16(__builtin_bit_cast(f16x8, a), \
                                         __builtin_bit_cast(f16x8, b), c, 0, 0, 0)

#define EXP2(x) exp2f(x)
#if __has_builtin(__builtin_amdgcn_rcpf)
#define RCP(x) __builtin_amdgcn_rcpf(x)
#else
#define RCP(x) (1.0f / (x))
#endif

#define LOG2E 1.44269504088896340736f
#define LN2   0.69314718055994530942f

// d_ws: f16 weight fragments (global, frag-linear)
#define OFF_FWB 0
#define OFF_WQB 8192
#define OFF_WKB 73728
#define OFF_WVB 139264
#define OFF_WOB 204800
#define OFF_W1B 270336
#define OFF_W2B 532480
// total 663552 B

// LDS (bytes): activation frag buffers + staged per-layer weights
#define L_Q 0
#define L_K 16384
#define L_V 32768
#define L_O 49152
#define LW_Q 65536
#define LW_K 73728
#define LW_V 81920
#define LW_O 90112
#define LW_1 98304
#define LW_2 131072
#define LDS_BYTES 147456

// Fragment slot bijection (prep kernel only)
__device__ __forceinline__ int fragSlotByte(int idx, int k, int KS) {
  return ((((idx >> 4) * KS + (k >> 5)) << 10)
        | (((idx & 15) | (((k >> 2) & 3) << 4)) << 4)
        | (((k & 3) | (((k >> 4) & 1) << 2)) << 1));
}
__device__ __forceinline__ short f2h(float f) {
  _Float16 h = (_Float16)f;
  return __builtin_bit_cast(short, h);
}
__device__ __forceinline__ float h2f(short s) {
  return (float)__builtin_bit_cast(_Float16, s);
}
__device__ __forceinline__ unsigned pk_u32(float a, float b) {
  return __builtin_bit_cast(unsigned, __builtin_amdgcn_cvt_pkrtz(a, b));
}
// erf via Abramowitz-Stegun 7.1.25 3-term (|err|<=2.5e-5)
__device__ __forceinline__ float geluf(float v) {
  float z = fabsf(v) * 0.70710678118654752f;
  float t = RCP(1.0f + 0.47047f * z);
  float p = t * (0.3480242f + t * (-0.0958798f + t * 0.7478556f));
  float erfv = 1.0f - p * __expf(-z * z);
  erfv = copysignf(erfv, v);
  return 0.5f * v * (1.0f + erfv);
}
__device__ __forceinline__ s16x8 pack8(const f32x4& a, const f32x4& b) {
  union { unsigned u[4]; s16x8 s; } z;
  z.u[0] = pk_u32(a[0], a[1]);
  z.u[1] = pk_u32(a[2], a[3]);
  z.u[2] = pk_u32(b[0], b[1]);
  z.u[3] = pk_u32(b[2], b[3]);
  return z.s;
}
__device__ __forceinline__ s16x4 pack4(const f32x4& a) {
  union { unsigned u[2]; s16x4 s; } z;
  z.u[0] = pk_u32(a[0], a[1]);
  z.u[1] = pk_u32(a[2], a[3]);
  return z.s;
}
__device__ __forceinline__ s16x8 fragL(const char* lds, int off, int tile, int lane) {
  return *(const s16x8*)(lds + off + (tile << 10) + (lane << 4));
}
__device__ __forceinline__ s16x8 fragG(const char* wb, int tile, int lane) {
  return *(const s16x8*)(wb + (tile << 10) + (lane << 4));
}

// async global->LDS 16B; frag-linear layout == wave-uniform base + lane*16
__device__ __forceinline__ void gl_lds16(const char* g, char* l) {
#if __has_builtin(__builtin_amdgcn_global_load_lds)
  __builtin_amdgcn_global_load_lds(
      (const __attribute__((address_space(1))) unsigned int*)g,
      (__attribute__((address_space(3))) unsigned int*)l, 16, 0, 0);
#else
  *(s16x8*)l = *(const s16x8*)g;
#endif
}
// stage `bytes` (multiple of 8192) with all 512 threads
__device__ __forceinline__ void stageW(const char* g, char* l, int bytes, int tid) {
  for (int off = tid * 16; off < bytes; off += 8192)
    gl_lds16(g + off, l + off);
}

// ---------------- weight prep: all fp32 weights -> f16 frag-linear ----------------
// Wq pre-scaled by 1/4 (1/sqrt(DQK)); Wo pre-scaled by ln2 (p*log2e carry domain).
extern "C" __global__ void prep_all(const float* __restrict__ fw, const float* __restrict__ wq,
                                    const float* __restrict__ wk, const float* __restrict__ wv,
                                    const float* __restrict__ wo, const float* __restrict__ w1,
                                    const float* __restrict__ w2, char* __restrict__ dst) {
  for (int e = blockIdx.x * blockDim.x + threadIdx.x; e < 331776; e += gridDim.x * blockDim.x) {
    const float* src; int dstoff, K, N, rel; float sc = 1.f;
    if (e < 4096)        { src = fw; dstoff = OFF_FWB; K = 64;  N = 64;  rel = e; }
    else if (e < 36864)  { src = wq; dstoff = OFF_WQB; K = 64;  N = 64;  rel = e - 4096; sc = 0.25f; }
    else if (e < 69632)  { src = wk; dstoff = OFF_WKB; K = 64;  N = 64;  rel = e - 36864; }
    else if (e < 102400) { src = wv; dstoff = OFF_WVB; K = 64;  N = 64;  rel = e - 69632; }
    else if (e < 135168) { src = wo; dstoff = OFF_WOB; K = 64;  N = 64;  rel = e - 102400; sc = LN2; }
    else if (e < 266240) { src = w1; dstoff = OFF_W1B; K = 64;  N = 256; rel = e - 135168; }
    else                 { src = w2; dstoff = OFF_W2B; K = 128; N = 64;  rel = e - 266240; }
    const int KS = K >> 5, pl = K * N;
    const int l = rel / pl, r2 = rel - l * pl;
    const int k = r2 / N, n = r2 - k * N;
    *(short*)(dst + dstoff + (size_t)l * pl * 2 + fragSlotByte(n, k, KS)) = f2h(src[rel] * sc);
  }
}

// ---------------- main fused kernel: 1 block = 1 batch, 8 waves ----------------
extern "C" __global__ __launch_bounds__(512)
void feat_fwd(const float* __restrict__ x, const float* __restrict__ cls_token,
              const float* __restrict__ pos_embed, const float* __restrict__ Wmix,
              const float* __restrict__ ln1_g, const float* __restrict__ ln1_b,
              const float* __restrict__ ln2_g, const float* __restrict__ ln2_b,
              const float* __restrict__ b1, const float* __restrict__ b2,
              const float* __restrict__ Wc, const float* __restrict__ bc,
              float* __restrict__ out, const char* __restrict__ wfrag) {
  extern __shared__ char lds[];
  const int tid = threadIdx.x, lane = tid & 63, wv = tid >> 6, b = blockIdx.x;
  const int l15 = lane & 15, g16 = lane >> 4;
  const f32x4 Z4 = {0.f, 0.f, 0.f, 0.f};

  f32x4 hr[4];
  s16x8 hp[2];
  s16x8 af[4][4] = {};

  // issue layer-0 wq/wk/wv staging; DMA overlaps P0 compute, drained by barrier below
  stageW(wfrag + OFF_WQB, lds + LW_Q, 8192, tid);
  stageW(wfrag + OFF_WKB, lds + LW_K, 8192, tid);
  stageW(wfrag + OFF_WVB, lds + LW_V, 8192, tid);

  // ---- P0: patch embed (W as A, x as B), C-init = pos_embed -> hr regs ----
  {
    const int i0 = wv * 16 + l15;
    s16x8 xB[2];
#pragma unroll
    for (int ks = 0; ks < 2; ++ks) {
      f32x4 lo, hi;
#pragma unroll
      for (int e = 0; e < 8; ++e) {
        int sidx = i0 * 16 + (e >> 2) * 16 + g16 * 4 + (e & 3);
        if (sidx > 2047) sidx = 2047;  // i0==127 lanes overridden below
        float xv = x[((size_t)b * 2048 + sidx) * 2 + ks];
        if (e < 4) lo[e] = xv; else hi[e - 4] = xv;
      }
      xB[ks] = pack8(lo, hi);
    }
    const char* fwb = wfrag + OFF_FWB;
#pragma unroll
    for (int nt = 0; nt < 4; ++nt) {
      f32x4 a = *(const f32x4*)&pos_embed[i0 * 64 + nt * 16 + g16 * 4];
      a = MFMA(fragG(fwb, nt * 2 + 0, lane), xB[0], a);
      a = MFMA(fragG(fwb, nt * 2 + 1, lane), xB[1], a);
      hr[nt] = a;
    }
    if (i0 == 127) {
#pragma unroll
      for (int nt = 0; nt < 4; ++nt) {
        const f32x4 c4 = *(const f32x4*)&cls_token[nt * 16 + g16 * 4];
        const f32x4 p4 = *(const f32x4*)&pos_embed[127 * 64 + nt * 16 + g16 * 4];
        hr[nt] = c4 + p4;
      }
    }
    hp[0] = pack8(hr[0], hr[1]);
    hp[1] = pack8(hr[2], hr[3]);
  }
  __syncthreads();  // drains weight DMA (vmcnt 0) + makes LW_Q/K/V visible

  for (int l = 0; l < 8; ++l) {
    // ---- P1: q,k (W as A) and v (normal) from hp regs + LDS weights -> LDS frags ----
    {
      f32x4 aq[4], ak[4], av[4];
#pragma unroll
      for (int nt = 0; nt < 4; ++nt) { aq[nt] = Z4; ak[nt] = Z4; av[nt] = Z4; }
#pragma unroll
      for (int ks = 0; ks < 2; ++ks)
#pragma unroll
        for (int nt = 0; nt < 4; ++nt) {
          aq[nt] = MFMA(fragL(lds, LW_Q, nt * 2 + ks, lane), hp[ks], aq[nt]);
          ak[nt] = MFMA(fragL(lds, LW_K, nt * 2 + ks, lane), hp[ks], ak[nt]);
          av[nt] = MFMA(hp[ks], fragL(lds, LW_V, nt * 2 + ks, lane), av[nt]);
        }
#pragma unroll
      for (int ksp = 0; ksp < 2; ++ksp) {
        *(s16x8*)(lds + L_Q + (((wv * 2 + ksp) << 10) | (lane << 4))) = pack8(aq[2 * ksp], aq[2 * ksp + 1]);
        *(s16x8*)(lds + L_K + (((wv * 2 + ksp) << 10) | (lane << 4))) = pack8(ak[2 * ksp], ak[2 * ksp + 1]);
      }
#pragma unroll
      for (int nt = 0; nt < 4; ++nt)  // v transposed frag: idx=vcol, k=row
        *(s16x4*)(lds + L_V + (((nt * 4 + (wv >> 1)) << 10) | (lane << 4) | ((wv & 1) << 3))) = pack4(av[nt]);
    }
    __syncthreads();  // barrier 1

    // prefetch: (a) next layer's wq/wk/wv (consumed at next P1, after barrier 2)
    //           (b) this layer's wo/W1/W2 (consumed at P4/P5/P6, after barrier 2)
    if (l < 7) {
      stageW(wfrag + OFF_WQB + (l + 1) * 8192, lds + LW_Q, 8192, tid);
      stageW(wfrag + OFF_WKB + (l + 1) * 8192, lds + LW_K, 8192, tid);
      stageW(wfrag + OFF_WVB + (l + 1) * 8192, lds + LW_V, 8192, tid);
    }
    stageW(wfrag + OFF_WOB + l * 8192, lds + LW_O, 8192, tid);
    stageW(wfrag + OFF_W1B + l * 32768, lds + LW_1, 32768, tid);
    stageW(wfrag + OFF_W2B + l * 16384, lds + LW_2, 16384, tid);

    // ---- P2: acc = LOG2E*(S + carry) via C-init; p*LOG2E = exp2(acc)/sum ----
    {
      const int g = wv >> 1, ih = wv & 1;
      s16x8 wmv[2];
      {
        const float w0 = Wmix[(l * 4 + 0) * 4 + g] * LOG2E, w1_ = Wmix[(l * 4 + 1) * 4 + g] * LOG2E;
        const float w2_ = Wmix[(l * 4 + 2) * 4 + g] * LOG2E, w3_ = Wmix[(l * 4 + 3) * 4 + g] * LOG2E;
        union { unsigned u[4]; s16x8 s; } u0, u1;
        u0.u[0] = u0.u[1] = pk_u32(w0, w0);
        u0.u[2] = u0.u[3] = pk_u32(w1_, w1_);
        u1.u[0] = u1.u[1] = pk_u32(w2_, w2_);
        u1.u[2] = u1.u[3] = pk_u32(w3_, w3_);
        wmv[0] = u0.s; wmv[1] = u1.s;
      }
#pragma unroll
      for (int q4 = 0; q4 < 4; ++q4) {
        const int ti = ih * 4 + q4;
        f32x4 acc[8];
        if (l > 0) {
#pragma unroll
          for (int jt = 0; jt < 8; ++jt)
#pragma unroll
            for (int r = 0; r < 4; ++r)
              acc[jt][r] = h2f(af[q4][jt >> 1][((jt & 1) << 2) | r]);
        } else {
#pragma unroll
          for (int jt = 0; jt < 8; ++jt) acc[jt] = Z4;
        }
#pragma unroll
        for (int ks = 0; ks < 2; ++ks) {
          const s16x8 qr = fragL(lds, L_Q, ti * 2 + ks, lane);
          const f16x8 qm = __builtin_bit_cast(f16x8, qr) * __builtin_bit_cast(f16x8, wmv[ks]);
#pragma unroll
          for (int jt = 0; jt < 8; ++jt)
            acc[jt] = MFMA(fragL(lds, L_K, jt * 2 + ks, lane), qm, acc[jt]);
        }
        float s0 = 0.f, s1 = 0.f, s2 = 0.f, s3 = 0.f;
#pragma unroll
        for (int jt = 0; jt < 8; ++jt) {
          const float e0 = EXP2(acc[jt][0]);
          const float e1 = EXP2(acc[jt][1]);
          const float e2 = EXP2(acc[jt][2]);
          const float e3 = EXP2(acc[jt][3]);
          acc[jt][0] = e0; acc[jt][1] = e1;
          acc[jt][2] = e2; acc[jt][3] = e3;
          s0 += e0; s1 += e1; s2 += e2; s3 += e3;
        }
        float s = (s0 + s1) + (s2 + s3);
        s += __shfl_xor(s, 16); s += __shfl_xor(s, 32);
        const float invl = RCP(s) * LOG2E;
#pragma unroll
        for (int jt = 0; jt < 8; ++jt) {
          acc[jt][0] *= invl; acc[jt][1] *= invl;
          acc[jt][2] *= invl; acc[jt][3] *= invl;
        }
#pragma unroll
        for (int ks3 = 0; ks3 < 4; ++ks3)
          af[q4][ks3] = pack8(acc[2 * ks3], acc[2 * ks3 + 1]);
      }
    }
    // no barrier: P3 reads L_V (ready) + own af; writes L_O (disjoint)

    // ---- P3: o' = v^T-frags (A) x (p*LOG2E) (B=af) -> L_O frags ----
    {
      const int g = wv >> 1, ih = wv & 1;
#pragma unroll
      for (int q4 = 0; q4 < 4; ++q4) {
        const int ti = ih * 4 + q4;
        f32x4 a = Z4;
#pragma unroll
        for (int ks = 0; ks < 4; ++ks)
          a = MFMA(fragL(lds, L_V, g * 4 + ks, lane), af[q4][ks], a);
        *(s16x4*)(lds + L_O + (((ti * 2 + (g >> 1)) << 10) | (lane << 4) | ((g & 1) << 3))) = pack4(a);
      }
    }
    __syncthreads();  // barrier 2: drains weight DMA + publishes L_O

    // ---- P4: r = o'@Wo' (LDS, C-init = hr); h = LN1 -> hr, hp ----
    {
      s16x8 ofr[2];
      ofr[0] = fragL(lds, L_O, wv * 2 + 0, lane);
      ofr[1] = fragL(lds, L_O, wv * 2 + 1, lane);
      f32x4 vv[4];
      float s = 0.f;
#pragma unroll
      for (int nt = 0; nt < 4; ++nt) {
        f32x4 a = hr[nt];
        a = MFMA(fragL(lds, LW_O, nt * 2 + 0, lane), ofr[0], a);
        a = MFMA(fragL(lds, LW_O, nt * 2 + 1, lane), ofr[1], a);
        vv[nt] = a;
        s += (a[0] + a[1]) + (a[2] + a[3]);
      }
      s += __shfl_xor(s, 16); s += __shfl_xor(s, 32);
      const float mu = s * 0.015625f;
      float sq = 0.f;
#pragma unroll
      for (int nt = 0; nt < 4; ++nt)
#pragma unroll
        for (int r = 0; r < 4; ++r) { float d = vv[nt][r] - mu; sq += d * d; }
      sq += __shfl_xor(sq, 16); sq += __shfl_xor(sq, 32);
      const float rs = rsqrtf(sq * 0.015625f + 1e-5f);
#pragma unroll
      for (int nt = 0; nt < 4; ++nt) {
        const f32x4 g4 = *(const f32x4*)&ln1_g[l * 64 + nt * 16 + g16 * 4];
        const f32x4 b4 = *(const f32x4*)&ln1_b[l * 64 + nt * 16 + g16 * 4];
#pragma unroll
        for (int r = 0; r < 4; ++r)
          hr[nt][r] = (vv[nt][r] - mu) * rs * g4[r] + b4[r];
      }
      hp[0] = pack8(hr[0], hr[1]);
      hp[1] = pack8(hr[2], hr[3]);
    }

    // ---- P5+P6 fused: u=h@W1 (C-init b1) -> GLU -> f -> h = LN2(h + f@W2 + b2) ----
    {
      f32x4 acc6[4];
#pragma unroll
      for (int nt = 0; nt < 4; ++nt) {
        const f32x4 bb = *(const f32x4*)&b2[l * 64 + nt * 16 + g16 * 4];
        acc6[nt] = hr[nt] + bb;
      }
#pragma unroll
      for (int ks6 = 0; ks6 < 4; ++ks6) {
        union { unsigned u[4]; s16x8 s; } fb;
#pragma unroll
        for (int half = 0; half < 2; ++half) {
          const int mtp = ks6 * 2 + half;
          f32x4 a1 = *(const f32x4*)&b1[l * 256 + mtp * 16 + g16 * 4];
          f32x4 a2 = *(const f32x4*)&b1[l * 256 + 128 + mtp * 16 + g16 * 4];
#pragma unroll
          for (int ks = 0; ks < 2; ++ks) {
            a1 = MFMA(fragL(lds, LW_1, mtp * 2 + ks, lane), hp[ks], a1);
            a2 = MFMA(fragL(lds, LW_1, (mtp + 8) * 2 + ks, lane), hp[ks], a2);
          }
          float fv[4];
#pragma unroll
          for (int r = 0; r < 4; ++r)
            fv[r] = a1[r] * geluf(a2[r]) + a2[r] * geluf(a1[r]);
          fb.u[half * 2 + 0] = pk_u32(fv[0], fv[1]);
          fb.u[half * 2 + 1] = pk_u32(fv[2], fv[3]);
        }
#pragma unroll
        for (int nt = 0; nt < 4; ++nt)
          acc6[nt] = MFMA(fragL(lds, LW_2, nt * 4 + ks6, lane), fb.s, acc6[nt]);
      }
      float s = 0.f;
#pragma unroll
      for (int nt = 0; nt < 4; ++nt)
        s += (acc6[nt][0] + acc6[nt][1]) + (acc6[nt][2] + acc6[nt][3]);
      s += __shfl_xor(s, 16); s += __shfl_xor(s, 32);
      const float mu = s * 0.015625f;
      float sq = 0.f;
#pragma unroll
      for (int nt = 0; nt < 4; ++nt)
#pragma unroll
        for (int r = 0; r < 4; ++r) { float d = acc6[nt][r] - mu; sq += d * d; }
      sq += __shfl_xor(sq, 16); sq += __shfl_xor(sq, 32);
      const float rs = rsqrtf(sq * 0.015625f + 1e-5f);
#pragma unroll
      for (int nt = 0; nt < 4; ++nt) {
        const f32x4 g4 = *(const f32x4*)&ln2_g[l * 64 + nt * 16 + g16 * 4];
        const f32x4 b4 = *(const f32x4*)&ln2_b[l * 64 + nt * 16 + g16 * 4];
#pragma unroll
        for (int r = 0; r < 4; ++r)
          hr[nt][r] = (acc6[nt][r] - mu) * rs * g4[r] + b4[r];
      }
      hp[0] = pack8(hr[0], hr[1]);
      hp[1] = pack8(hr[2], hr[3]);
    }
  }

  // ---- classifier head on row 127 ----
  float* scr = (float*)(lds + L_Q);
  if (wv == 7 && l15 == 15) {
#pragma unroll
    for (int nt = 0; nt < 4; ++nt)
#pragma unroll
      for (int r = 0; r < 4; ++r) scr[nt * 16 + g16 * 4 + r] = hr[nt][r];
  }
  __syncthreads();
  if (wv == 0) {
    const float hc = scr[lane];
    float lg[11];
#pragma unroll
    for (int kc = 0; kc < 11; ++kc) {
      float p = hc * Wc[lane * 11 + kc];
      p += __shfl_xor(p, 1);  p += __shfl_xor(p, 2);  p += __shfl_xor(p, 4);
      p += __shfl_xor(p, 8);  p += __shfl_xor(p, 16); p += __shfl_xor(p, 32);
      lg[kc] = p + bc[kc];
    }
    float mx = lg[0];
#pragma unroll
    for (int kc = 1; kc < 11; ++kc) mx = fmaxf(mx, lg[kc]);
    float s = 0.f;
#pragma unroll
    for (int kc = 0; kc < 11; ++kc) s += __expf(lg[kc] - mx);
    const float inv = 1.f / s;
    if (lane < 11) out[b * 11 + lane] = __expf(lg[lane] - mx) * inv;
  }
}

extern "C" void kernel_launch(void* const* d_in, const int* in_sizes, int n_in,
                              void* d_out, int out_size, void* d_ws, size_t ws_size,
                              hipStream_t stream) {
  const float* x         = (const float*)d_in[0];
  const float* frame_W   = (const float*)d_in[1];
  const float* cls_token = (const float*)d_in[2];
  const float* pos_embed = (const float*)d_in[3];
  const float* Wq        = (const float*)d_in[4];
  const float* Wk        = (const float*)d_in[5];
  const float* Wv        = (const float*)d_in[6];
  const float* Wmix      = (const float*)d_in[7];
  const float* Wo        = (const float*)d_in[8];
  const float* ln1_g     = (const float*)d_in[9];
  const float* ln1_b     = (const float*)d_in[10];
  const float* ln2_g     = (const float*)d_in[11];
  const float* ln2_b     = (const float*)d_in[12];
  const float* W1        = (const float*)d_in[13];
  const float* b1        = (const float*)d_in[14];
  const float* W2        = (const float*)d_in[15];
  const float* b2        = (const float*)d_in[16];
  const float* Wc        = (const float*)d_in[17];
  const float* bc        = (const float*)d_in[18];
  float* out = (float*)d_out;
  char* wfrag = (char*)d_ws;  // 663,552 B of f16 weight fragments

  prep_all<<<162, 256, 0, stream>>>(frame_W, Wq, Wk, Wv, Wo, W1, W2, wfrag);

  (void)hipFuncSetAttribute((const void*)feat_fwd, hipFuncAttributeMaxDynamicSharedMemorySize, LDS_BYTES);
  feat_fwd<<<dim3(256), dim3(512), LDS_BYTES, stream>>>(
      x, cls_token, pos_embed, Wmix, ln1_g, ln1_b, ln2_g, ln2_b,
      b1, b2, Wc, bc, out, wfrag);
}

// Round 10
// 104.807 us; speedup vs baseline: 2.1164x; 1.1804x over previous
//
#include <hip/hip_runtime.h>
#include <hip/hip_bf16.h>
#include <math.h>

typedef short s16x8 __attribute__((ext_vector_type(8)));
typedef short s16x4 __attribute__((ext_vector_type(4)));
typedef _Float16 f16x8 __attribute__((ext_vector_type(8)));
typedef float f32x4 __attribute__((ext_vector_type(4)));
typedef unsigned u32x4 __attribute__((ext_vector_type(4)));

#define MFMA(a, b, c) \
  __builtin_amdgcn_mfma_f32_16x16x32_f16(__builtin_bit_cast(f16x8, a), \
                                         __builtin_bit_cast(f16x8, b), c, 0, 0, 0)

#define LOG2E 1.44269504088896340736f
#define LN2   0.69314718055994530942f

__device__ __forceinline__ float ex2(float x) {   // single v_exp_f32 (D = 2^S0)
#if __has_builtin(__builtin_amdgcn_exp2f)
  return __builtin_amdgcn_exp2f(x);
#else
  float r; asm("v_exp_f32 %0, %1" : "=v"(r) : "v"(x)); return r;
#endif
}
__device__ __forceinline__ float rcpf_(float x) {  // single v_rcp_f32
#if __has_builtin(__builtin_amdgcn_rcpf)
  return __builtin_amdgcn_rcpf(x);
#else
  float r; asm("v_rcp_f32 %0, %1" : "=v"(r) : "v"(x)); return r;
#endif
}
__device__ __forceinline__ f32x4 splat(float x) { f32x4 r = {x, x, x, x}; return r; }

// d_ws: f16 weight fragments (global, frag-linear)
#define OFF_FWB 0
#define OFF_WQB 8192
#define OFF_WKB 73728
#define OFF_WVB 139264
#define OFF_WOB 204800
#define OFF_W1B 270336
#define OFF_W2B 532480
// total 663552 B

// LDS (bytes)
#define L_Q 0
#define L_K 16384
#define L_V 32768
#define L_O 49152
#define LW_Q 65536
#define LW_K 73728
#define LW_V 81920
#define LW_O 90112
#define LW_1 98304
#define LW_2 131072
#define L_B1 147456   // b1 fp32, all layers, 8 KiB
#define LDS_BYTES 155648

// Fragment slot bijection (prep kernel only)
__device__ __forceinline__ int fragSlotByte(int idx, int k, int KS) {
  return ((((idx >> 4) * KS + (k >> 5)) << 10)
        | (((idx & 15) | (((k >> 2) & 3) << 4)) << 4)
        | (((k & 3) | (((k >> 4) & 1) << 2)) << 1));
}
__device__ __forceinline__ short f2h(float f) {
  _Float16 h = (_Float16)f;
  return __builtin_bit_cast(short, h);
}
__device__ __forceinline__ float h2f(short s) {
  return (float)__builtin_bit_cast(_Float16, s);
}
__device__ __forceinline__ unsigned pk_u32(float a, float b) {
  return __builtin_bit_cast(unsigned, __builtin_amdgcn_cvt_pkrtz(a, b));
}
// vectorized GELU: erf via A&S 7.1.25 3-term; poly/muls in packed f32, exp/rcp scalar
__device__ __forceinline__ f32x4 gelu4(const f32x4& v) {
  const u32x4 bits = __builtin_bit_cast(u32x4, v);
  const u32x4 sgn = bits & 0x80000000u;
  const f32x4 av = __builtin_bit_cast(f32x4, bits & 0x7fffffffu);
  const f32x4 z = av * splat(0.70710678118654752f);
  const f32x4 den = z * splat(0.47047f) + splat(1.0f);
  f32x4 t;
  t[0] = rcpf_(den[0]); t[1] = rcpf_(den[1]); t[2] = rcpf_(den[2]); t[3] = rcpf_(den[3]);
  const f32x4 p = t * (splat(0.3480242f) + t * (splat(-0.0958798f) + t * splat(0.7478556f)));
  const f32x4 m = v * v * splat(-0.72134752044448170368f);  // -log2e/2
  f32x4 e;
  e[0] = ex2(m[0]); e[1] = ex2(m[1]); e[2] = ex2(m[2]); e[3] = ex2(m[3]);
  const f32x4 erfa = splat(1.0f) - p * e;                   // >= 0
  const f32x4 erfv = __builtin_bit_cast(f32x4, __builtin_bit_cast(u32x4, erfa) | sgn);
  return splat(0.5f) * v * (splat(1.0f) + erfv);
}
__device__ __forceinline__ s16x8 pack8(const f32x4& a, const f32x4& b) {
  union { unsigned u[4]; s16x8 s; } z;
  z.u[0] = pk_u32(a[0], a[1]);
  z.u[1] = pk_u32(a[2], a[3]);
  z.u[2] = pk_u32(b[0], b[1]);
  z.u[3] = pk_u32(b[2], b[3]);
  return z.s;
}
__device__ __forceinline__ s16x4 pack4(const f32x4& a) {
  union { unsigned u[2]; s16x4 s; } z;
  z.u[0] = pk_u32(a[0], a[1]);
  z.u[1] = pk_u32(a[2], a[3]);
  return z.s;
}
__device__ __forceinline__ s16x8 fragL(const char* lds, int off, int tile, int lane) {
  return *(const s16x8*)(lds + off + (tile << 10) + (lane << 4));
}
__device__ __forceinline__ s16x8 fragG(const char* wb, int tile, int lane) {
  return *(const s16x8*)(wb + (tile << 10) + (lane << 4));
}

// async global->LDS 16B; frag-linear layout == wave-uniform base + lane*16
__device__ __forceinline__ void gl_lds16(const char* g, char* l) {
#if __has_builtin(__builtin_amdgcn_global_load_lds)
  __builtin_amdgcn_global_load_lds(
      (const __attribute__((address_space(1))) unsigned int*)g,
      (__attribute__((address_space(3))) unsigned int*)l, 16, 0, 0);
#else
  *(s16x8*)l = *(const s16x8*)g;
#endif
}
__device__ __forceinline__ void stageW(const char* g, char* l, int bytes, int tid) {
  for (int off = tid * 16; off < bytes; off += 8192)
    gl_lds16(g + off, l + off);
}

// ---------------- weight prep ----------------
// Wq pre-scaled by 1/4; Wo pre-scaled by ln2 (p*log2e carry domain).
extern "C" __global__ void prep_all(const float* __restrict__ fw, const float* __restrict__ wq,
                                    const float* __restrict__ wk, const float* __restrict__ wv,
                                    const float* __restrict__ wo, const float* __restrict__ w1,
                                    const float* __restrict__ w2, char* __restrict__ dst) {
  for (int e = blockIdx.x * blockDim.x + threadIdx.x; e < 331776; e += gridDim.x * blockDim.x) {
    const float* src; int dstoff, K, N, rel; float sc = 1.f;
    if (e < 4096)        { src = fw; dstoff = OFF_FWB; K = 64;  N = 64;  rel = e; }
    else if (e < 36864)  { src = wq; dstoff = OFF_WQB; K = 64;  N = 64;  rel = e - 4096; sc = 0.25f; }
    else if (e < 69632)  { src = wk; dstoff = OFF_WKB; K = 64;  N = 64;  rel = e - 36864; }
    else if (e < 102400) { src = wv; dstoff = OFF_WVB; K = 64;  N = 64;  rel = e - 69632; }
    else if (e < 135168) { src = wo; dstoff = OFF_WOB; K = 64;  N = 64;  rel = e - 102400; sc = LN2; }
    else if (e < 266240) { src = w1; dstoff = OFF_W1B; K = 64;  N = 256; rel = e - 135168; }
    else                 { src = w2; dstoff = OFF_W2B; K = 128; N = 64;  rel = e - 266240; }
    const int KS = K >> 5, pl = K * N;
    const int l = rel / pl, r2 = rel - l * pl;
    const int k = r2 / N, n = r2 - k * N;
    *(short*)(dst + dstoff + (size_t)l * pl * 2 + fragSlotByte(n, k, KS)) = f2h(src[rel] * sc);
  }
}

// ---------------- main fused kernel: 1 block = 1 batch, 8 waves ----------------
extern "C" __global__ __launch_bounds__(512)
void feat_fwd(const float* __restrict__ x, const float* __restrict__ cls_token,
              const float* __restrict__ pos_embed, const float* __restrict__ Wmix,
              const float* __restrict__ ln1_g, const float* __restrict__ ln1_b,
              const float* __restrict__ ln2_g, const float* __restrict__ ln2_b,
              const float* __restrict__ b1, const float* __restrict__ b2,
              const float* __restrict__ Wc, const float* __restrict__ bc,
              float* __restrict__ out, const char* __restrict__ wfrag) {
  extern __shared__ char lds[];
  const int tid = threadIdx.x, lane = tid & 63, wv = tid >> 6, b = blockIdx.x;
  const int l15 = lane & 15, g16 = lane >> 4;
  const f32x4 Z4 = {0.f, 0.f, 0.f, 0.f};

  f32x4 hr[4];
  s16x8 hp[2];
  s16x8 af[4][4] = {};

  // layer-0 wq/wk/wv + all-layer b1 staging; overlaps P0, drained by barrier below
  stageW(wfrag + OFF_WQB, lds + LW_Q, 8192, tid);
  stageW(wfrag + OFF_WKB, lds + LW_K, 8192, tid);
  stageW(wfrag + OFF_WVB, lds + LW_V, 8192, tid);
  stageW((const char*)b1, lds + L_B1, 8192, tid);

  // ---- P0: patch embed (W as A, x as B), C-init = pos_embed -> hr regs ----
  {
    const int i0 = wv * 16 + l15;
    s16x8 xB[2];
#pragma unroll
    for (int ks = 0; ks < 2; ++ks) {
      f32x4 lo, hi;
#pragma unroll
      for (int e = 0; e < 8; ++e) {
        int sidx = i0 * 16 + (e >> 2) * 16 + g16 * 4 + (e & 3);
        if (sidx > 2047) sidx = 2047;  // i0==127 lanes overridden below
        float xv = x[((size_t)b * 2048 + sidx) * 2 + ks];
        if (e < 4) lo[e] = xv; else hi[e - 4] = xv;
      }
      xB[ks] = pack8(lo, hi);
    }
    const char* fwb = wfrag + OFF_FWB;
#pragma unroll
    for (int nt = 0; nt < 4; ++nt) {
      f32x4 a = *(const f32x4*)&pos_embed[i0 * 64 + nt * 16 + g16 * 4];
      a = MFMA(fragG(fwb, nt * 2 + 0, lane), xB[0], a);
      a = MFMA(fragG(fwb, nt * 2 + 1, lane), xB[1], a);
      hr[nt] = a;
    }
    if (i0 == 127) {
#pragma unroll
      for (int nt = 0; nt < 4; ++nt) {
        const f32x4 c4 = *(const f32x4*)&cls_token[nt * 16 + g16 * 4];
        const f32x4 p4 = *(const f32x4*)&pos_embed[127 * 64 + nt * 16 + g16 * 4];
        hr[nt] = c4 + p4;
      }
    }
    hp[0] = pack8(hr[0], hr[1]);
    hp[1] = pack8(hr[2], hr[3]);
  }
  __syncthreads();  // drains DMA, publishes LW_Q/K/V + L_B1

  for (int l = 0; l < 8; ++l) {
    // ---- P1: q,k (W as A) and v from hp + LDS weights -> LDS frags ----
    {
      f32x4 aq[4], ak[4], av[4];
#pragma unroll
      for (int nt = 0; nt < 4; ++nt) { aq[nt] = Z4; ak[nt] = Z4; av[nt] = Z4; }
#pragma unroll
      for (int ks = 0; ks < 2; ++ks)
#pragma unroll
        for (int nt = 0; nt < 4; ++nt) {
          aq[nt] = MFMA(fragL(lds, LW_Q, nt * 2 + ks, lane), hp[ks], aq[nt]);
          ak[nt] = MFMA(fragL(lds, LW_K, nt * 2 + ks, lane), hp[ks], ak[nt]);
          av[nt] = MFMA(hp[ks], fragL(lds, LW_V, nt * 2 + ks, lane), av[nt]);
        }
#pragma unroll
      for (int ksp = 0; ksp < 2; ++ksp) {
        *(s16x8*)(lds + L_Q + (((wv * 2 + ksp) << 10) | (lane << 4))) = pack8(aq[2 * ksp], aq[2 * ksp + 1]);
        *(s16x8*)(lds + L_K + (((wv * 2 + ksp) << 10) | (lane << 4))) = pack8(ak[2 * ksp], ak[2 * ksp + 1]);
      }
#pragma unroll
      for (int nt = 0; nt < 4; ++nt)
        *(s16x4*)(lds + L_V + (((nt * 4 + (wv >> 1)) << 10) | (lane << 4) | ((wv & 1) << 3))) = pack4(av[nt]);
    }
    __syncthreads();  // barrier 1

    // prefetch next-layer wq/wk/wv + this-layer wo/W1/W2
    if (l < 7) {
      stageW(wfrag + OFF_WQB + (l + 1) * 8192, lds + LW_Q, 8192, tid);
      stageW(wfrag + OFF_WKB + (l + 1) * 8192, lds + LW_K, 8192, tid);
      stageW(wfrag + OFF_WVB + (l + 1) * 8192, lds + LW_V, 8192, tid);
    }
    stageW(wfrag + OFF_WOB + l * 8192, lds + LW_O, 8192, tid);
    stageW(wfrag + OFF_W1B + l * 32768, lds + LW_1, 32768, tid);
    stageW(wfrag + OFF_W2B + l * 16384, lds + LW_2, 16384, tid);

    // ---- P2: acc = LOG2E*(S + carry) via C-init; p*LOG2E = exp2(acc)/sum ----
    {
      const int g = wv >> 1, ih = wv & 1;
      s16x8 wmv[2];
      {
        const float w0 = Wmix[(l * 4 + 0) * 4 + g] * LOG2E, w1_ = Wmix[(l * 4 + 1) * 4 + g] * LOG2E;
        const float w2_ = Wmix[(l * 4 + 2) * 4 + g] * LOG2E, w3_ = Wmix[(l * 4 + 3) * 4 + g] * LOG2E;
        union { unsigned u[4]; s16x8 s; } u0, u1;
        u0.u[0] = u0.u[1] = pk_u32(w0, w0);
        u0.u[2] = u0.u[3] = pk_u32(w1_, w1_);
        u1.u[0] = u1.u[1] = pk_u32(w2_, w2_);
        u1.u[2] = u1.u[3] = pk_u32(w3_, w3_);
        wmv[0] = u0.s; wmv[1] = u1.s;
      }
#pragma unroll
      for (int q4 = 0; q4 < 4; ++q4) {
        const int ti = ih * 4 + q4;
        f32x4 acc[8];
        if (l > 0) {
#pragma unroll
          for (int jt = 0; jt < 8; ++jt)
#pragma unroll
            for (int r = 0; r < 4; ++r)
              acc[jt][r] = h2f(af[q4][jt >> 1][((jt & 1) << 2) | r]);
        } else {
#pragma unroll
          for (int jt = 0; jt < 8; ++jt) acc[jt] = Z4;
        }
#pragma unroll
        for (int ks = 0; ks < 2; ++ks) {
          const s16x8 qr = fragL(lds, L_Q, ti * 2 + ks, lane);
          const f16x8 qm = __builtin_bit_cast(f16x8, qr) * __builtin_bit_cast(f16x8, wmv[ks]);
#pragma unroll
          for (int jt = 0; jt < 8; ++jt)
            acc[jt] = MFMA(fragL(lds, L_K, jt * 2 + ks, lane), qm, acc[jt]);
        }
        // softmax (no max-shift; |logit| small); exp scalar, sum/scale packed
        f32x4 sv = Z4;
#pragma unroll
        for (int jt = 0; jt < 8; ++jt) {
          acc[jt][0] = ex2(acc[jt][0]);
          acc[jt][1] = ex2(acc[jt][1]);
          acc[jt][2] = ex2(acc[jt][2]);
          acc[jt][3] = ex2(acc[jt][3]);
          sv += acc[jt];
        }
        float s = (sv[0] + sv[1]) + (sv[2] + sv[3]);
        s += __shfl_xor(s, 16); s += __shfl_xor(s, 32);
        const float invl = rcpf_(s) * LOG2E;
        const f32x4 iv = splat(invl);
#pragma unroll
        for (int jt = 0; jt < 8; ++jt) acc[jt] *= iv;
#pragma unroll
        for (int ks3 = 0; ks3 < 4; ++ks3)
          af[q4][ks3] = pack8(acc[2 * ks3], acc[2 * ks3 + 1]);
      }
    }
    // no barrier: P3 reads L_V (ready) + own af; writes L_O (disjoint)

    // ---- P3: o' = v^T (A) x (p*LOG2E) (B=af) -> L_O frags ----
    {
      const int g = wv >> 1, ih = wv & 1;
#pragma unroll
      for (int q4 = 0; q4 < 4; ++q4) {
        const int ti = ih * 4 + q4;
        f32x4 a = Z4;
#pragma unroll
        for (int ks = 0; ks < 4; ++ks)
          a = MFMA(fragL(lds, L_V, g * 4 + ks, lane), af[q4][ks], a);
        *(s16x4*)(lds + L_O + (((ti * 2 + (g >> 1)) << 10) | (lane << 4) | ((g & 1) << 3))) = pack4(a);
      }
    }
    __syncthreads();  // barrier 2: drains weight DMA + publishes L_O

    // ---- P4: r = o'@Wo' (C-init = hr); h = LN1 -> hr, hp ----
    {
      s16x8 ofr[2];
      ofr[0] = fragL(lds, L_O, wv * 2 + 0, lane);
      ofr[1] = fragL(lds, L_O, wv * 2 + 1, lane);
      f32x4 vv[4];
      f32x4 sv = Z4;
#pragma unroll
      for (int nt = 0; nt < 4; ++nt) {
        f32x4 a = hr[nt];
        a = MFMA(fragL(lds, LW_O, nt * 2 + 0, lane), ofr[0], a);
        a = MFMA(fragL(lds, LW_O, nt * 2 + 1, lane), ofr[1], a);
        vv[nt] = a;
        sv += a;
      }
      float s = (sv[0] + sv[1]) + (sv[2] + sv[3]);
      s += __shfl_xor(s, 16); s += __shfl_xor(s, 32);
      const float mu = s * 0.015625f;
      const f32x4 mu4 = splat(mu);
      f32x4 d[4], q = Z4;
#pragma unroll
      for (int nt = 0; nt < 4; ++nt) { d[nt] = vv[nt] - mu4; q += d[nt] * d[nt]; }
      float sq = (q[0] + q[1]) + (q[2] + q[3]);
      sq += __shfl_xor(sq, 16); sq += __shfl_xor(sq, 32);
      const float rs = rsqrtf(sq * 0.015625f + 1e-5f);
      const f32x4 rs4 = splat(rs);
#pragma unroll
      for (int nt = 0; nt < 4; ++nt) {
        const f32x4 g4 = *(const f32x4*)&ln1_g[l * 64 + nt * 16 + g16 * 4];
        const f32x4 b4 = *(const f32x4*)&ln1_b[l * 64 + nt * 16 + g16 * 4];
        hr[nt] = d[nt] * rs4 * g4 + b4;
      }
      hp[0] = pack8(hr[0], hr[1]);
      hp[1] = pack8(hr[2], hr[3]);
    }

    // ---- P5+P6: u=h@W1 (C-init = b1 from LDS) -> GLU -> f -> h = LN2(h+f@W2+b2) ----
    {
      f32x4 acc6[4];
#pragma unroll
      for (int nt = 0; nt < 4; ++nt) {
        const f32x4 bb = *(const f32x4*)&b2[l * 64 + nt * 16 + g16 * 4];
        acc6[nt] = hr[nt] + bb;
      }
#pragma unroll
      for (int ks6 = 0; ks6 < 4; ++ks6) {
        union { unsigned u[4]; s16x8 s; } fb;
#pragma unroll
        for (int half = 0; half < 2; ++half) {
          const int mtp = ks6 * 2 + half;
          f32x4 a1 = *(const f32x4*)(lds + L_B1 + (l * 256 + mtp * 16 + g16 * 4) * 4);
          f32x4 a2 = *(const f32x4*)(lds + L_B1 + (l * 256 + 128 + mtp * 16 + g16 * 4) * 4);
#pragma unroll
          for (int ks = 0; ks < 2; ++ks) {
            a1 = MFMA(fragL(lds, LW_1, mtp * 2 + ks, lane), hp[ks], a1);
            a2 = MFMA(fragL(lds, LW_1, (mtp + 8) * 2 + ks, lane), hp[ks], a2);
          }
          const f32x4 fv = a1 * gelu4(a2) + a2 * gelu4(a1);
          fb.u[half * 2 + 0] = pk_u32(fv[0], fv[1]);
          fb.u[half * 2 + 1] = pk_u32(fv[2], fv[3]);
        }
#pragma unroll
        for (int nt = 0; nt < 4; ++nt)
          acc6[nt] = MFMA(fragL(lds, LW_2, nt * 4 + ks6, lane), fb.s, acc6[nt]);
      }
      f32x4 sv = Z4;
#pragma unroll
      for (int nt = 0; nt < 4; ++nt) sv += acc6[nt];
      float s = (sv[0] + sv[1]) + (sv[2] + sv[3]);
      s += __shfl_xor(s, 16); s += __shfl_xor(s, 32);
      const float mu = s * 0.015625f;
      const f32x4 mu4 = splat(mu);
      f32x4 d[4], q = Z4;
#pragma unroll
      for (int nt = 0; nt < 4; ++nt) { d[nt] = acc6[nt] - mu4; q += d[nt] * d[nt]; }
      float sq = (q[0] + q[1]) + (q[2] + q[3]);
      sq += __shfl_xor(sq, 16); sq += __shfl_xor(sq, 32);
      const float rs = rsqrtf(sq * 0.015625f + 1e-5f);
      const f32x4 rs4 = splat(rs);
#pragma unroll
      for (int nt = 0; nt < 4; ++nt) {
        const f32x4 g4 = *(const f32x4*)&ln2_g[l * 64 + nt * 16 + g16 * 4];
        const f32x4 b4 = *(const f32x4*)&ln2_b[l * 64 + nt * 16 + g16 * 4];
        hr[nt] = d[nt] * rs4 * g4 + b4;
      }
      hp[0] = pack8(hr[0], hr[1]);
      hp[1] = pack8(hr[2], hr[3]);
    }
  }

  // ---- classifier head on row 127 ----
  float* scr = (float*)(lds + L_Q);
  if (wv == 7 && l15 == 15) {
#pragma unroll
    for (int nt = 0; nt < 4; ++nt)
#pragma unroll
      for (int r = 0; r < 4; ++r) scr[nt * 16 + g16 * 4 + r] = hr[nt][r];
  }
  __syncthreads();
  if (wv == 0) {
    const float hc = scr[lane];
    float lg[11];
#pragma unroll
    for (int kc = 0; kc < 11; ++kc) {
      float p = hc * Wc[lane * 11 + kc];
      p += __shfl_xor(p, 1);  p += __shfl_xor(p, 2);  p += __shfl_xor(p, 4);
      p += __shfl_xor(p, 8);  p += __shfl_xor(p, 16); p += __shfl_xor(p, 32);
      lg[kc] = p + bc[kc];
    }
    float mx = lg[0];
#pragma unroll
    for (int kc = 1; kc < 11; ++kc) mx = fmaxf(mx, lg[kc]);
    float s = 0.f;
#pragma unroll
    for (int kc = 0; kc < 11; ++kc) s += __expf(lg[kc] - mx);
    const float inv = 1.f / s;
    if (lane < 11) out[b * 11 + lane] = __expf(lg[lane] - mx) * inv;
  }
}

extern "C" void kernel_launch(void* const* d_in, const int* in_sizes, int n_in,
                              void* d_out, int out_size, void* d_ws, size_t ws_size,
                              hipStream_t stream) {
  const float* x         = (const float*)d_in[0];
  const float* frame_W   = (const float*)d_in[1];
  const float* cls_token = (const float*)d_in[2];
  const float* pos_embed = (const float*)d_in[3];
  const float* Wq        = (const float*)d_in[4];
  const float* Wk        = (const float*)d_in[5];
  const float* Wv        = (const float*)d_in[6];
  const float* Wmix      = (const float*)d_in[7];
  const float* Wo        = (const float*)d_in[8];
  const float* ln1_g     = (const float*)d_in[9];
  const float* ln1_b     = (const float*)d_in[10];
  const float* ln2_g     = (const float*)d_in[11];
  const float* ln2_b     = (const float*)d_in[12];
  const float* W1        = (const float*)d_in[13];
  const float* b1        = (const float*)d_in[14];
  const float* W2        = (const float*)d_in[15];
  const float* b2        = (const float*)d_in[16];
  const float* Wc        = (const float*)d_in[17];
  const float* bc        = (const float*)d_in[18];
  float* out = (float*)d_out;
  char* wfrag = (char*)d_ws;  // 663,552 B of f16 weight fragments

  prep_all<<<162, 256, 0, stream>>>(frame_W, Wq, Wk, Wv, Wo, W1, W2, wfrag);

  (void)hipFuncSetAttribute((const void*)feat_fwd, hipFuncAttributeMaxDynamicSharedMemorySize, LDS_BYTES);
  feat_fwd<<<dim3(256), dim3(512), LDS_BYTES, stream>>>(
      x, cls_token, pos_embed, Wmix, ln1_g, ln1_b, ln2_g, ln2_b,
      b1, b2, Wc, bc, out, wfrag);
}

// Round 11
// 96.236 us; speedup vs baseline: 2.3049x; 1.0891x over previous
//
#include <hip/hip_runtime.h>
#include <hip/hip_bf16.h>
#include <math.h>

typedef short s16x8 __attribute__((ext_vector_type(8)));
typedef short s16x4 __attribute__((ext_vector_type(4)));
typedef _Float16 f16x8 __attribute__((ext_vector_type(8)));
typedef float f32x4 __attribute__((ext_vector_type(4)));
typedef unsigned u32x4 __attribute__((ext_vector_type(4)));

#define MFMA(a, b, c) \
  __builtin_amdgcn_mfma_f32_16x16x32_f16(__builtin_bit_cast(f16x8, a), \
                                         __builtin_bit_cast(f16x8, b), c, 0, 0, 0)

#define LOG2E 1.44269504088896340736f
#define LN2   0.69314718055994530942f

__device__ __forceinline__ float ex2(float x) {   // single v_exp_f32 (D = 2^S0)
#if __has_builtin(__builtin_amdgcn_exp2f)
  return __builtin_amdgcn_exp2f(x);
#else
  float r; asm("v_exp_f32 %0, %1" : "=v"(r) : "v"(x)); return r;
#endif
}
__device__ __forceinline__ float rcpf_(float x) {  // single v_rcp_f32
#if __has_builtin(__builtin_amdgcn_rcpf)
  return __builtin_amdgcn_rcpf(x);
#else
  float r; asm("v_rcp_f32 %0, %1" : "=v"(r) : "v"(x)); return r;
#endif
}
__device__ __forceinline__ f32x4 splat(float x) { f32x4 r = {x, x, x, x}; return r; }

// d_ws: f16 weight fragments (global, frag-linear)
#define OFF_FWB 0
#define OFF_WQB 8192
#define OFF_WKB 73728
#define OFF_WVB 139264
#define OFF_WOB 204800
#define OFF_W1B 270336
#define OFF_W2B 532480
// total 663552 B

// LDS (bytes)
#define L_Q 0
#define L_K 16384
#define L_V 32768
#define L_O 49152
#define LW_Q 65536
#define LW_K 73728
#define LW_V 81920
#define LW_O 90112
#define LW_1 98304
#define LW_2 131072
#define L_B1 147456   // b1 fp32, all layers, 8 KiB
#define LDS_BYTES 155648

// Fragment slot bijection (prep kernel only)
__device__ __forceinline__ int fragSlotByte(int idx, int k, int KS) {
  return ((((idx >> 4) * KS + (k >> 5)) << 10)
        | (((idx & 15) | (((k >> 2) & 3) << 4)) << 4)
        | (((k & 3) | (((k >> 4) & 1) << 2)) << 1));
}
__device__ __forceinline__ short f2h(float f) {
  _Float16 h = (_Float16)f;
  return __builtin_bit_cast(short, h);
}
__device__ __forceinline__ unsigned pk_u32(float a, float b) {
  return __builtin_bit_cast(unsigned, __builtin_amdgcn_cvt_pkrtz(a, b));
}
// tanh-form GELU: gelu(x) = x * sigma(2y), y = sqrt(2/pi)(x + 0.044715 x^3)
// = x * rcp(1 + exp2(w*x*(1 + 0.044715 x^2))), w = -2*log2e*sqrt(2/pi)
// max |diff vs exact erf-GELU| ~1e-3. 18 packed instrs, no sign handling.
__device__ __forceinline__ f32x4 gelu4(const f32x4& v) {
  const f32x4 x2 = v * v;
  const f32x4 inner = splat(-2.30258930213f) + x2 * splat(-0.102970317236f); // w, w*0.044715
  const f32x4 arg = v * inner;
  f32x4 e;
  e[0] = ex2(arg[0]); e[1] = ex2(arg[1]); e[2] = ex2(arg[2]); e[3] = ex2(arg[3]);
  const f32x4 den = splat(1.0f) + e;
  f32x4 r;
  r[0] = rcpf_(den[0]); r[1] = rcpf_(den[1]); r[2] = rcpf_(den[2]); r[3] = rcpf_(den[3]);
  return v * r;
}
__device__ __forceinline__ s16x8 pack8(const f32x4& a, const f32x4& b) {
  union { unsigned u[4]; s16x8 s; } z;
  z.u[0] = pk_u32(a[0], a[1]);
  z.u[1] = pk_u32(a[2], a[3]);
  z.u[2] = pk_u32(b[0], b[1]);
  z.u[3] = pk_u32(b[2], b[3]);
  return z.s;
}
__device__ __forceinline__ s16x4 pack4(const f32x4& a) {
  union { unsigned u[2]; s16x4 s; } z;
  z.u[0] = pk_u32(a[0], a[1]);
  z.u[1] = pk_u32(a[2], a[3]);
  return z.s;
}
__device__ __forceinline__ s16x8 fragL(const char* lds, int off, int tile, int lane) {
  return *(const s16x8*)(lds + off + (tile << 10) + (lane << 4));
}
__device__ __forceinline__ s16x8 fragG(const char* wb, int tile, int lane) {
  return *(const s16x8*)(wb + (tile << 10) + (lane << 4));
}

// async global->LDS 16B; frag-linear layout == wave-uniform base + lane*16
__device__ __forceinline__ void gl_lds16(const char* g, char* l) {
#if __has_builtin(__builtin_amdgcn_global_load_lds)
  __builtin_amdgcn_global_load_lds(
      (const __attribute__((address_space(1))) unsigned int*)g,
      (__attribute__((address_space(3))) unsigned int*)l, 16, 0, 0);
#else
  *(s16x8*)l = *(const s16x8*)g;
#endif
}
__device__ __forceinline__ void stageW(const char* g, char* l, int bytes, int tid) {
  for (int off = tid * 16; off < bytes; off += 8192)
    gl_lds16(g + off, l + off);
}

// ---------------- weight prep ----------------
// Wq pre-scaled by 1/4; Wo pre-scaled by ln2 (p*log2e carry domain).
extern "C" __global__ void prep_all(const float* __restrict__ fw, const float* __restrict__ wq,
                                    const float* __restrict__ wk, const float* __restrict__ wv,
                                    const float* __restrict__ wo, const float* __restrict__ w1,
                                    const float* __restrict__ w2, char* __restrict__ dst) {
  for (int e = blockIdx.x * blockDim.x + threadIdx.x; e < 331776; e += gridDim.x * blockDim.x) {
    const float* src; int dstoff, K, N, rel; float sc = 1.f;
    if (e < 4096)        { src = fw; dstoff = OFF_FWB; K = 64;  N = 64;  rel = e; }
    else if (e < 36864)  { src = wq; dstoff = OFF_WQB; K = 64;  N = 64;  rel = e - 4096; sc = 0.25f; }
    else if (e < 69632)  { src = wk; dstoff = OFF_WKB; K = 64;  N = 64;  rel = e - 36864; }
    else if (e < 102400) { src = wv; dstoff = OFF_WVB; K = 64;  N = 64;  rel = e - 69632; }
    else if (e < 135168) { src = wo; dstoff = OFF_WOB; K = 64;  N = 64;  rel = e - 102400; sc = LN2; }
    else if (e < 266240) { src = w1; dstoff = OFF_W1B; K = 64;  N = 256; rel = e - 135168; }
    else                 { src = w2; dstoff = OFF_W2B; K = 128; N = 64;  rel = e - 266240; }
    const int KS = K >> 5, pl = K * N;
    const int l = rel / pl, r2 = rel - l * pl;
    const int k = r2 / N, n = r2 - k * N;
    *(short*)(dst + dstoff + (size_t)l * pl * 2 + fragSlotByte(n, k, KS)) = f2h(src[rel] * sc);
  }
}

// ---------------- main fused kernel: 1 block = 1 batch, 8 waves ----------------
// launch_bounds(512,1): VGPR cap 256. Occupancy is LDS-bound (152KB -> 1 block/CU
// = 8 waves/CU) regardless, so the f32 carry (128 VGPR) costs no occupancy.
extern "C" __global__ __launch_bounds__(512, 1)
void feat_fwd(const float* __restrict__ x, const float* __restrict__ cls_token,
              const float* __restrict__ pos_embed, const float* __restrict__ Wmix,
              const float* __restrict__ ln1_g, const float* __restrict__ ln1_b,
              const float* __restrict__ ln2_g, const float* __restrict__ ln2_b,
              const float* __restrict__ b1, const float* __restrict__ b2,
              const float* __restrict__ Wc, const float* __restrict__ bc,
              float* __restrict__ out, const char* __restrict__ wfrag) {
  extern __shared__ char lds[];
  const int tid = threadIdx.x, lane = tid & 63, wv = tid >> 6, b = blockIdx.x;
  const int l15 = lane & 15, g16 = lane >> 4;
  const f32x4 Z4 = {0.f, 0.f, 0.f, 0.f};

  f32x4 hr[4];
  s16x8 hp[2];
  // fp32 carry in p*LOG2E domain; doubles as the QK^T MFMA accumulator (C-init).
  f32x4 af32[4][8];
#pragma unroll
  for (int q4 = 0; q4 < 4; ++q4)
#pragma unroll
    for (int jt = 0; jt < 8; ++jt) af32[q4][jt] = Z4;

  // layer-0 wq/wk/wv + all-layer b1 staging; overlaps P0, drained by barrier below
  stageW(wfrag + OFF_WQB, lds + LW_Q, 8192, tid);
  stageW(wfrag + OFF_WKB, lds + LW_K, 8192, tid);
  stageW(wfrag + OFF_WVB, lds + LW_V, 8192, tid);
  stageW((const char*)b1, lds + L_B1, 8192, tid);

  // ---- P0: patch embed (W as A, x as B), C-init = pos_embed -> hr regs ----
  {
    const int i0 = wv * 16 + l15;
    s16x8 xB[2];
#pragma unroll
    for (int ks = 0; ks < 2; ++ks) {
      f32x4 lo, hi;
#pragma unroll
      for (int e = 0; e < 8; ++e) {
        int sidx = i0 * 16 + (e >> 2) * 16 + g16 * 4 + (e & 3);
        if (sidx > 2047) sidx = 2047;  // i0==127 lanes overridden below
        float xv = x[((size_t)b * 2048 + sidx) * 2 + ks];
        if (e < 4) lo[e] = xv; else hi[e - 4] = xv;
      }
      xB[ks] = pack8(lo, hi);
    }
    const char* fwb = wfrag + OFF_FWB;
#pragma unroll
    for (int nt = 0; nt < 4; ++nt) {
      f32x4 a = *(const f32x4*)&pos_embed[i0 * 64 + nt * 16 + g16 * 4];
      a = MFMA(fragG(fwb, nt * 2 + 0, lane), xB[0], a);
      a = MFMA(fragG(fwb, nt * 2 + 1, lane), xB[1], a);
      hr[nt] = a;
    }
    if (i0 == 127) {
#pragma unroll
      for (int nt = 0; nt < 4; ++nt) {
        const f32x4 c4 = *(const f32x4*)&cls_token[nt * 16 + g16 * 4];
        const f32x4 p4 = *(const f32x4*)&pos_embed[127 * 64 + nt * 16 + g16 * 4];
        hr[nt] = c4 + p4;
      }
    }
    hp[0] = pack8(hr[0], hr[1]);
    hp[1] = pack8(hr[2], hr[3]);
  }
  __syncthreads();  // drains DMA, publishes LW_Q/K/V + L_B1

  for (int l = 0; l < 8; ++l) {
    // ---- P1: q,k (W as A) and v from hp + LDS weights -> LDS frags ----
    {
      f32x4 aq[4], ak[4], av[4];
#pragma unroll
      for (int nt = 0; nt < 4; ++nt) { aq[nt] = Z4; ak[nt] = Z4; av[nt] = Z4; }
#pragma unroll
      for (int ks = 0; ks < 2; ++ks)
#pragma unroll
        for (int nt = 0; nt < 4; ++nt) {
          aq[nt] = MFMA(fragL(lds, LW_Q, nt * 2 + ks, lane), hp[ks], aq[nt]);
          ak[nt] = MFMA(fragL(lds, LW_K, nt * 2 + ks, lane), hp[ks], ak[nt]);
          av[nt] = MFMA(hp[ks], fragL(lds, LW_V, nt * 2 + ks, lane), av[nt]);
        }
#pragma unroll
      for (int ksp = 0; ksp < 2; ++ksp) {
        *(s16x8*)(lds + L_Q + (((wv * 2 + ksp) << 10) | (lane << 4))) = pack8(aq[2 * ksp], aq[2 * ksp + 1]);
        *(s16x8*)(lds + L_K + (((wv * 2 + ksp) << 10) | (lane << 4))) = pack8(ak[2 * ksp], ak[2 * ksp + 1]);
      }
#pragma unroll
      for (int nt = 0; nt < 4; ++nt)
        *(s16x4*)(lds + L_V + (((nt * 4 + (wv >> 1)) << 10) | (lane << 4) | ((wv & 1) << 3))) = pack4(av[nt]);
    }
    __syncthreads();  // barrier 1

    // prefetch next-layer wq/wk/wv + this-layer wo/W1/W2
    if (l < 7) {
      stageW(wfrag + OFF_WQB + (l + 1) * 8192, lds + LW_Q, 8192, tid);
      stageW(wfrag + OFF_WKB + (l + 1) * 8192, lds + LW_K, 8192, tid);
      stageW(wfrag + OFF_WVB + (l + 1) * 8192, lds + LW_V, 8192, tid);
    }
    stageW(wfrag + OFF_WOB + l * 8192, lds + LW_O, 8192, tid);
    stageW(wfrag + OFF_W1B + l * 32768, lds + LW_1, 32768, tid);
    stageW(wfrag + OFF_W2B + l * 16384, lds + LW_2, 16384, tid);

    // ---- P2: af32 += LOG2E*S (MFMA in place); p*LOG2E = exp2(af32)/sum ----
    {
      const int g = wv >> 1, ih = wv & 1;
      s16x8 wmv[2];
      {
        const float w0 = Wmix[(l * 4 + 0) * 4 + g] * LOG2E, w1_ = Wmix[(l * 4 + 1) * 4 + g] * LOG2E;
        const float w2_ = Wmix[(l * 4 + 2) * 4 + g] * LOG2E, w3_ = Wmix[(l * 4 + 3) * 4 + g] * LOG2E;
        union { unsigned u[4]; s16x8 s; } u0, u1;
        u0.u[0] = u0.u[1] = pk_u32(w0, w0);
        u0.u[2] = u0.u[3] = pk_u32(w1_, w1_);
        u1.u[0] = u1.u[1] = pk_u32(w2_, w2_);
        u1.u[2] = u1.u[3] = pk_u32(w3_, w3_);
        wmv[0] = u0.s; wmv[1] = u1.s;
      }
#pragma unroll
      for (int q4 = 0; q4 < 4; ++q4) {
        const int ti = ih * 4 + q4;
#pragma unroll
        for (int ks = 0; ks < 2; ++ks) {
          const s16x8 qr = fragL(lds, L_Q, ti * 2 + ks, lane);
          const f16x8 qm = __builtin_bit_cast(f16x8, qr) * __builtin_bit_cast(f16x8, wmv[ks]);
#pragma unroll
          for (int jt = 0; jt < 8; ++jt)
            af32[q4][jt] = MFMA(fragL(lds, L_K, jt * 2 + ks, lane), qm, af32[q4][jt]);
        }
        // softmax (no max-shift; |logit| small); exp scalar, sum/scale packed
        f32x4 sv = Z4;
#pragma unroll
        for (int jt = 0; jt < 8; ++jt) {
          af32[q4][jt][0] = ex2(af32[q4][jt][0]);
          af32[q4][jt][1] = ex2(af32[q4][jt][1]);
          af32[q4][jt][2] = ex2(af32[q4][jt][2]);
          af32[q4][jt][3] = ex2(af32[q4][jt][3]);
          sv += af32[q4][jt];
        }
        float s = (sv[0] + sv[1]) + (sv[2] + sv[3]);
        s += __shfl_xor(s, 16); s += __shfl_xor(s, 32);
        const float invl = rcpf_(s) * LOG2E;
        const f32x4 iv = splat(invl);
#pragma unroll
        for (int jt = 0; jt < 8; ++jt) af32[q4][jt] *= iv;
      }
    }
    // no barrier: P3 reads L_V (ready) + own af32; writes L_O (disjoint)

    // ---- P3: o' = v^T (A) x (p*LOG2E) (B packed on the fly) -> L_O frags ----
    {
      const int g = wv >> 1, ih = wv & 1;
#pragma unroll
      for (int q4 = 0; q4 < 4; ++q4) {
        const int ti = ih * 4 + q4;
        f32x4 a = Z4;
#pragma unroll
        for (int ks = 0; ks < 4; ++ks) {
          const s16x8 pfrag = pack8(af32[q4][2 * ks], af32[q4][2 * ks + 1]);
          a = MFMA(fragL(lds, L_V, g * 4 + ks, lane), pfrag, a);
        }
        *(s16x4*)(lds + L_O + (((ti * 2 + (g >> 1)) << 10) | (lane << 4) | ((g & 1) << 3))) = pack4(a);
      }
    }
    __syncthreads();  // barrier 2: drains weight DMA + publishes L_O

    // ---- P4: r = o'@Wo' (C-init = hr); h = LN1 -> hr, hp ----
    {
      s16x8 ofr[2];
      ofr[0] = fragL(lds, L_O, wv * 2 + 0, lane);
      ofr[1] = fragL(lds, L_O, wv * 2 + 1, lane);
      f32x4 vv[4];
      f32x4 sv = Z4;
#pragma unroll
      for (int nt = 0; nt < 4; ++nt) {
        f32x4 a = hr[nt];
        a = MFMA(fragL(lds, LW_O, nt * 2 + 0, lane), ofr[0], a);
        a = MFMA(fragL(lds, LW_O, nt * 2 + 1, lane), ofr[1], a);
        vv[nt] = a;
        sv += a;
      }
      float s = (sv[0] + sv[1]) + (sv[2] + sv[3]);
      s += __shfl_xor(s, 16); s += __shfl_xor(s, 32);
      const float mu = s * 0.015625f;
      const f32x4 mu4 = splat(mu);
      f32x4 d[4], q = Z4;
#pragma unroll
      for (int nt = 0; nt < 4; ++nt) { d[nt] = vv[nt] - mu4; q += d[nt] * d[nt]; }
      float sq = (q[0] + q[1]) + (q[2] + q[3]);
      sq += __shfl_xor(sq, 16); sq += __shfl_xor(sq, 32);
      const float rs = rsqrtf(sq * 0.015625f + 1e-5f);
      const f32x4 rs4 = splat(rs);
#pragma unroll
      for (int nt = 0; nt < 4; ++nt) {
        const f32x4 g4 = *(const f32x4*)&ln1_g[l * 64 + nt * 16 + g16 * 4];
        const f32x4 b4 = *(const f32x4*)&ln1_b[l * 64 + nt * 16 + g16 * 4];
        hr[nt] = d[nt] * rs4 * g4 + b4;
      }
      hp[0] = pack8(hr[0], hr[1]);
      hp[1] = pack8(hr[2], hr[3]);
    }

    // ---- P5+P6: u=h@W1 (C-init = b1 from LDS) -> GLU -> f -> h = LN2(h+f@W2+b2) ----
    {
      f32x4 acc6[4];
#pragma unroll
      for (int nt = 0; nt < 4; ++nt) {
        const f32x4 bb = *(const f32x4*)&b2[l * 64 + nt * 16 + g16 * 4];
        acc6[nt] = hr[nt] + bb;
      }
#pragma unroll
      for (int ks6 = 0; ks6 < 4; ++ks6) {
        union { unsigned u[4]; s16x8 s; } fb;
#pragma unroll
        for (int half = 0; half < 2; ++half) {
          const int mtp = ks6 * 2 + half;
          f32x4 a1 = *(const f32x4*)(lds + L_B1 + (l * 256 + mtp * 16 + g16 * 4) * 4);
          f32x4 a2 = *(const f32x4*)(lds + L_B1 + (l * 256 + 128 + mtp * 16 + g16 * 4) * 4);
#pragma unroll
          for (int ks = 0; ks < 2; ++ks) {
            a1 = MFMA(fragL(lds, LW_1, mtp * 2 + ks, lane), hp[ks], a1);
            a2 = MFMA(fragL(lds, LW_1, (mtp + 8) * 2 + ks, lane), hp[ks], a2);
          }
          const f32x4 fv = a1 * gelu4(a2) + a2 * gelu4(a1);
          fb.u[half * 2 + 0] = pk_u32(fv[0], fv[1]);
          fb.u[half * 2 + 1] = pk_u32(fv[2], fv[3]);
        }
#pragma unroll
        for (int nt = 0; nt < 4; ++nt)
          acc6[nt] = MFMA(fragL(lds, LW_2, nt * 4 + ks6, lane), fb.s, acc6[nt]);
      }
      f32x4 sv = Z4;
#pragma unroll
      for (int nt = 0; nt < 4; ++nt) sv += acc6[nt];
      float s = (sv[0] + sv[1]) + (sv[2] + sv[3]);
      s += __shfl_xor(s, 16); s += __shfl_xor(s, 32);
      const float mu = s * 0.015625f;
      const f32x4 mu4 = splat(mu);
      f32x4 d[4], q = Z4;
#pragma unroll
      for (int nt = 0; nt < 4; ++nt) { d[nt] = acc6[nt] - mu4; q += d[nt] * d[nt]; }
      float sq = (q[0] + q[1]) + (q[2] + q[3]);
      sq += __shfl_xor(sq, 16); sq += __shfl_xor(sq, 32);
      const float rs = rsqrtf(sq * 0.015625f + 1e-5f);
      const f32x4 rs4 = splat(rs);
#pragma unroll
      for (int nt = 0; nt < 4; ++nt) {
        const f32x4 g4 = *(const f32x4*)&ln2_g[l * 64 + nt * 16 + g16 * 4];
        const f32x4 b4 = *(const f32x4*)&ln2_b[l * 64 + nt * 16 + g16 * 4];
        hr[nt] = d[nt] * rs4 * g4 + b4;
      }
      hp[0] = pack8(hr[0], hr[1]);
      hp[1] = pack8(hr[2], hr[3]);
    }
  }

  // ---- classifier head on row 127 ----
  float* scr = (float*)(lds + L_Q);
  if (wv == 7 && l15 == 15) {
#pragma unroll
    for (int nt = 0; nt < 4; ++nt)
#pragma unroll
      for (int r = 0; r < 4; ++r) scr[nt * 16 + g16 * 4 + r] = hr[nt][r];
  }
  __syncthreads();
  if (wv == 0) {
    const float hc = scr[lane];
    float lg[11];
#pragma unroll
    for (int kc = 0; kc < 11; ++kc) {
      float p = hc * Wc[lane * 11 + kc];
      p += __shfl_xor(p, 1);  p += __shfl_xor(p, 2);  p += __shfl_xor(p, 4);
      p += __shfl_xor(p, 8);  p += __shfl_xor(p, 16); p += __shfl_xor(p, 32);
      lg[kc] = p + bc[kc];
    }
    float mx = lg[0];
#pragma unroll
    for (int kc = 1; kc < 11; ++kc) mx = fmaxf(mx, lg[kc]);
    float s = 0.f;
#pragma unroll
    for (int kc = 0; kc < 11; ++kc) s += __expf(lg[kc] - mx);
    const float inv = 1.f / s;
    if (lane < 11) out[b * 11 + lane] = __expf(lg[lane] - mx) * inv;
  }
}

extern "C" void kernel_launch(void* const* d_in, const int* in_sizes, int n_in,
                              void* d_out, int out_size, void* d_ws, size_t ws_size,
                              hipStream_t stream) {
  const float* x         = (const float*)d_in[0];
  const float* frame_W   = (const float*)d_in[1];
  const float* cls_token = (const float*)d_in[2];
  const float* pos_embed = (const float*)d_in[3];
  const float* Wq        = (const float*)d_in[4];
  const float* Wk        = (const float*)d_in[5];
  const float* Wv        = (const float*)d_in[6];
  const float* Wmix      = (const float*)d_in[7];
  const float* Wo        = (const float*)d_in[8];
  const float* ln1_g     = (const float*)d_in[9];
  const float* ln1_b     = (const float*)d_in[10];
  const float* ln2_g     = (const float*)d_in[11];
  const float* ln2_b     = (const float*)d_in[12];
  const float* W1        = (const float*)d_in[13];
  const float* b1        = (const float*)d_in[14];
  const float* W2        = (const float*)d_in[15];
  const float* b2        = (const float*)d_in[16];
  const float* Wc        = (const float*)d_in[17];
  const float* bc        = (const float*)d_in[18];
  float* out = (float*)d_out;
  char* wfrag = (char*)d_ws;  // 663,552 B of f16 weight fragments

  prep_all<<<162, 256, 0, stream>>>(frame_W, Wq, Wk, Wv, Wo, W1, W2, wfrag);

  (void)hipFuncSetAttribute((const void*)feat_fwd, hipFuncAttributeMaxDynamicSharedMemorySize, LDS_BYTES);
  feat_fwd<<<dim3(256), dim3(512), LDS_BYTES, stream>>>(
      x, cls_token, pos_embed, Wmix, ln1_g, ln1_b, ln2_g, ln2_b,
      b1, b2, Wc, bc, out, wfrag);
}